// Round 8
// baseline (1140.100 us; speedup 1.0000x reference)
//
#include <hip/hip_runtime.h>
#include <cmath>
#include <cstdint>
#include <cstring>
#include <cstdlib>
#include <vector>
#include <algorithm>
#include <complex>

#define TILE 32

typedef __attribute__((ext_vector_type(8))) _Float16 f16x8;
typedef __attribute__((ext_vector_type(4))) float f32x4;

// ------------------------------------------------------------------
// TP tables: branch-free cg [40][16]; structural path tables for the
// out phase (fan 4/6/3 per class); alphas folded into W2.
// ------------------------------------------------------------------
struct TPTables {
  uint32_t cg1p[40*16*2];   // [slot][16] uint2 {prodidx(i*16+j), coefbits}
  uint32_t tabA[12];        // [grp(i3=0,2,4)][4 paths] = w0 | sbase<<16
  uint32_t tabB[6];         // i3=6 paths
  uint32_t tabC[3];         // i3=7 paths
  uint32_t cg2p[32*4*2];    // uint2 {i | j<<8, coefbits}
  uint32_t out2p[32];       // widx | s<<16
  float alpha1[272];
  float alpha2[32];
};

static double factd(int n){ double r=1; for(int i=2;i<=n;i++) r*=(double)i; return r; }

static double cg_complex(int j1,int m1,int j2,int m2,int j3,int m3){
  if(m1+m2!=m3) return 0.0;
  double pref = std::sqrt((2*j3+1)*factd(j3+j1-j2)*factd(j3-j1+j2)*factd(j1+j2-j3)/factd(j1+j2+j3+1));
  pref *= std::sqrt(factd(j3+m3)*factd(j3-m3)*factd(j1-m1)*factd(j1+m1)*factd(j2-m2)*factd(j2+m2));
  double s=0.0;
  for(int k=0;k<=j1+j2-j3;k++){
    int dd[6] = {k, j1+j2-j3-k, j1-m1-k, j2+m2-k, j3-j2+m1+k, j3-j1-m2+k};
    bool ok=true; double prod=1.0;
    for(int t=0;t<6;t++){ if(dd[t]<0){ok=false;break;} prod*=factd(dd[t]); }
    if(!ok) continue;
    s += ((k&1)?-1.0:1.0)/prod;
  }
  return pref*s;
}

typedef std::complex<double> cd;
static void real_U(int l, cd* U){
  int n = 2*l+1;
  for(int i=0;i<n*n;i++) U[i]=cd(0,0);
  U[l*n+l] = cd(1,0);
  for(int m=1;m<=l;m++){
    double sgn = (m&1)? -1.0 : 1.0;
    double is2 = 1.0/std::sqrt(2.0);
    U[(l+m)*n + (l+m)] = cd(sgn*is2,0);
    U[(l+m)*n + (l-m)] = cd(is2,0);
    U[(l-m)*n + (l+m)] = cd(0,-sgn*is2);
    U[(l-m)*n + (l-m)] = cd(0,is2);
  }
}

static void real_cg_h(int l1,int l2,int l3, double* out){
  int n1=2*l1+1,n2=2*l2+1,n3=2*l3+1;
  std::vector<cd> C(n1*n2*n3);
  for(int a=-l1;a<=l1;a++)for(int b=-l2;b<=l2;b++)for(int c=-l3;c<=l3;c++)
    C[(size_t)((a+l1)*n2+(b+l2))*n3+(c+l3)] = cd(cg_complex(l1,a,l2,b,l3,c),0);
  std::vector<cd> U1(n1*n1),U2(n2*n2),U3(n3*n3);
  real_U(l1,U1.data()); real_U(l2,U2.data()); real_U(l3,U3.data());
  std::vector<cd> T((size_t)n1*n2*n3, cd(0,0));
  for(int i=0;i<n1;i++)for(int j=0;j<n2;j++)for(int k=0;k<n3;k++){
    cd acc(0,0);
    for(int a=0;a<n1;a++){ cd u1=U1[i*n1+a]; if(u1==cd(0,0)) continue;
      for(int b=0;b<n2;b++){ cd u2=U2[j*n2+b]; if(u2==cd(0,0)) continue;
        for(int c=0;c<n3;c++){ cd u3=std::conj(U3[k*n3+c]); if(u3==cd(0,0)) continue;
          acc += u1*u2*u3*C[(size_t)(a*n2+b)*n3+c];
        } } }
    T[(size_t)(i*n2+j)*n3+k]=acc;
  }
  double sr=0, si=0;
  for(auto&z:T){ sr += std::fabs(z.real()); si += std::fabs(z.imag()); }
  int tot=n1*n2*n3;
  std::vector<double> R(tot);
  for(int i=0;i<tot;i++) R[i] = (sr>=si)? T[i].real() : T[i].imag();
  double nrm=0; for(double v:R) nrm += v*v; nrm = std::sqrt(nrm);
  for(int i=0;i<tot;i++) out[i] = R[i]/nrm;
}

struct HIrr{int m,l,p;};
static int map_id(int i){return i;}
static int map_gate(int i){return (i<16)? i : i-16;}

static void build_one(const std::vector<HIrr>& ir1, const std::vector<HIrr>& ir2,
                      const std::vector<HIrr>& ir3, int (*map1)(int),
                      std::vector<uint32_t>& cg_pk, std::vector<float>& cg_c,
                      std::vector<uint32_t>& out_pk, std::vector<float>& out_c)
{
  int n1=(int)ir1.size(), n2=(int)ir2.size(), n3=(int)ir3.size();
  std::vector<int> s1(n1), s2(n2), s3(n3);
  { int o=0; for(int i=0;i<n1;i++){ s1[i]=o; o+=ir1[i].m*(2*ir1[i].l+1);} }
  { int o=0; for(int i=0;i<n2;i++){ s2[i]=o; o+=ir2[i].m*(2*ir2[i].l+1);} }
  { int o=0; for(int i=0;i<n3;i++){ s3[i]=o; o+=ir3[i].m*(2*ir3[i].l+1);} }
  struct Inst{int i1,i2,i3,w0;};
  std::vector<Inst> insts; int woff=0;
  for(int i1=0;i1<n1;i1++)for(int i2=0;i2<n2;i2++)for(int i3=0;i3<n3;i3++){
    const HIrr&A=ir1[i1];const HIrr&B=ir2[i2];const HIrr&C=ir3[i3];
    int dl = A.l-B.l; if(dl<0) dl=-dl;
    if(A.p*B.p==C.p && dl<=C.l && C.l<=A.l+B.l){
      insts.push_back({i1,i2,i3,woff}); woff += A.m*B.m*C.m;
    }
  }
  std::vector<int> fan(n3,0);
  for(auto&P:insts) fan[P.i3] += ir1[P.i1].m*ir2[P.i2].m;
  int sbase=0;
  for(auto&P:insts){
    const HIrr&A=ir1[P.i1];const HIrr&B=ir2[P.i2];const HIrr&C=ir3[P.i3];
    int d1=2*A.l+1,d2=2*B.l+1,d3=2*C.l+1;
    double cg[343];
    real_cg_h(A.l,B.l,C.l,cg);
    double alpha = std::sqrt((double)d3/(double)fan[P.i3]);
    for(int u=0;u<A.m;u++)for(int v=0;v<B.m;v++){
      for(int k=0;k<d3;k++)
        for(int i=0;i<d1;i++)for(int j=0;j<d2;j++){
          double c = cg[(i*d2+j)*d3+k];
          if(std::fabs(c)<1e-8) continue;
          int iabs = map1(s1[P.i1]+u*d1+i);
          int jabs = s2[P.i2]+v*d2+j;
          cg_pk.push_back((uint32_t)iabs | ((uint32_t)jabs<<8) | ((uint32_t)(sbase+k)<<16));
          cg_c.push_back((float)c);
        }
      for(int w=0;w<C.m;w++)for(int k=0;k<d3;k++){
        out_pk.push_back((uint32_t)(s3[P.i3]+w*d3+k) | ((uint32_t)(P.w0+(u*B.m+v)*C.m+w)<<8) | ((uint32_t)(sbase+k)<<20));
        out_c.push_back((float)alpha);
      }
      sbase += d3;
    }
  }
}

static uint32_t fbits(float f){ uint32_t u; memcpy(&u,&f,4); return u; }

static void build_tables(TPTables& T){
  std::vector<HIrr> IR_SH   ={{1,0,1},{1,1,-1},{1,2,1},{1,3,-1}};
  std::vector<HIrr> GATE_IN ={{16,0,1},{16,0,-1},{8,0,1},{8,0,-1},{8,0,1},{8,0,-1},{16,1,-1},{16,1,1}};
  std::vector<HIrr> GATE_OUT={{16,0,1},{16,0,-1},{16,1,-1},{16,1,1}};
  std::vector<HIrr> IR_OUT  ={{1,0,1}};
  std::vector<uint32_t> cg1,o1,cg2,o2; std::vector<float> cg1c,o1c,cg2c,o2c;
  build_one(IR_SH,IR_SH,GATE_IN,map_id,cg1,cg1c,o1,o1c);
  build_one(GATE_OUT,IR_SH,IR_OUT,map_gate,cg2,cg2c,o2,o2c);
  memset(&T,0,sizeof(T));
  {
    int cnt[40]; memset(cnt,0,sizeof(cnt));
    for(size_t idx=0; idx<cg1.size(); ++idx){
      int i = cg1[idx]&0xff, j=(cg1[idx]>>8)&0xff, s=(int)(cg1[idx]>>16);
      uint32_t pidx = (uint32_t)(i*16+j);
      if(s<40 && cnt[s]<16){
        T.cg1p[(s*16+cnt[s])*2]   = pidx;
        T.cg1p[(s*16+cnt[s])*2+1] = fbits(cg1c[idx]);
        cnt[s]++;
      }
    }
  }
  {
    int GIl[8]={0,0,0,0,0,0,1,1}, GIp[8]={1,-1,1,-1,1,-1,-1,1}, GIm[8]={16,16,8,8,8,8,16,16};
    int SHl[4]={0,1,2,3}, SHp[4]={1,-1,1,-1};
    int w0=0, sb=0, nA0=0,nA1=0,nA2=0,nB=0,nC=0;
    for(int i1=0;i1<4;i1++)for(int i2=0;i2<4;i2++)for(int i3=0;i3<8;i3++){
      int dl=SHl[i1]-SHl[i2]; if(dl<0) dl=-dl;
      if(SHp[i1]*SHp[i2]==GIp[i3] && dl<=GIl[i3] && GIl[i3]<=SHl[i1]+SHl[i2]){
        uint32_t ent = (uint32_t)w0 | ((uint32_t)sb<<16);
        if(i3==0 && nA0<4) T.tabA[nA0++] = ent;
        else if(i3==2 && nA1<4) T.tabA[4+nA1++] = ent;
        else if(i3==4 && nA2<4) T.tabA[8+nA2++] = ent;
        else if(i3==6 && nB<6) T.tabB[nB++] = ent;
        else if(i3==7 && nC<3) T.tabC[nC++] = ent;
        w0 += GIm[i3];
        sb += 2*GIl[i3]+1;
      }
    }
  }
  for(size_t idx=0; idx<o1.size(); ++idx){
    int widx = (o1[idx]>>8)&0xfff;
    if(widx<272) T.alpha1[widx] = o1c[idx];
  }
  {
    int cnt[32]; memset(cnt,0,sizeof(cnt));
    for(size_t idx=0; idx<cg2.size(); ++idx){
      int s = (int)(cg2[idx]>>16);
      if(s<32 && cnt[s]<4){
        T.cg2p[(s*4+cnt[s])*2]   = cg2[idx]&0xFFFF;
        T.cg2p[(s*4+cnt[s])*2+1] = fbits(cg2c[idx]);
        cnt[s]++;
      }
    }
  }
  for(size_t idx=0; idx<o2.size() && idx<32; ++idx){
    int widx = (o2[idx]>>8)&0xfff;
    int s    = (int)(o2[idx]>>20);
    T.out2p[idx] = (uint32_t)widx | ((uint32_t)s<<16);
    if(widx<32) T.alpha2[widx] = o2c[idx];
  }
}

// ---------------- device helpers ----------------
__device__ __forceinline__ unsigned short f2h(float f){
  _Float16 h = (_Float16)f;
  unsigned short u; __builtin_memcpy(&u, &h, 2); return u;
}
__device__ __forceinline__ float h2f(unsigned short u){
  _Float16 h; __builtin_memcpy(&h, &u, 2); return (float)h;
}
// bank-spread bijection on 6-bit lane ids (rotate right 2)
__device__ __forceinline__ int sig(int x){ return ((x&3)<<4) | (x>>2); }

__device__ __forceinline__ void sph16(float x,float y,float z,float* sh){
  float x2=x*x, y2=y*y, z2=z*z;
  const float SQ3=1.7320508075688772f, SQ5=2.23606797749979f, SQ7=2.6457513110645907f;
  const float SQ15=3.872983346207417f, SQ42=6.48074069840786f, SQ70=8.366600265340756f, SQ105=10.246950765959598f;
  sh[0]=1.f;
  sh[1]=SQ3*y;  sh[2]=SQ3*z;  sh[3]=SQ3*x;
  sh[4]=SQ15*x*y; sh[5]=SQ15*y*z; sh[6]=0.5f*SQ5*(3.f*z2-1.f); sh[7]=SQ15*x*z; sh[8]=0.5f*SQ15*(x2-y2);
  sh[9]=0.25f*SQ70*y*(3.f*x2-y2); sh[10]=SQ105*x*y*z; sh[11]=0.25f*SQ42*y*(5.f*z2-1.f);
  sh[12]=0.5f*SQ7*z*(5.f*z2-3.f); sh[13]=0.25f*SQ42*x*(5.f*z2-1.f);
  sh[14]=0.5f*SQ105*z*(x2-y2);    sh[15]=0.25f*SQ70*x*(x2-3.f*y2);
}

__device__ __forceinline__ void radial10(float d, float* emb){
  const float step = 0.2909090909090909f;
  #pragma unroll
  for(int b=0;b<10;b++){
    float c = step*(float)(b+1);
    float u = (d-c)/step;
    float u2 = u*u;
    float f = 0.f;
    if(u2<1.f) f = 1.14136f*__expf(-u2/fmaxf(1.f-u2,1e-6f));
    emb[b] = f*3.1622776601683795f;
  }
}

// ---------------- kernels ----------------
__global__ void k_zero(float* a, size_t na, float* b, size_t nb, float* c, size_t nc,
                       int* d, size_t nd){
  size_t total = na+nb+nc+nd;
  for(size_t i = (size_t)blockIdx.x*blockDim.x+threadIdx.x; i<total; i += (size_t)gridDim.x*blockDim.x){
    if(i<na) a[i]=0.f;
    else if(i<na+nb) b[i-na]=0.f;
    else if(i<na+nb+nc) c[i-na-nb]=0.f;
    else d[i-na-nb-nc]=0;
  }
}

__global__ void k_deg(const int* __restrict__ edst, int* __restrict__ deg, int E){
  int e = blockIdx.x*256 + threadIdx.x;
  if(e<E) atomicAdd(&deg[edst[e]], 1);
}

__global__ __launch_bounds__(1024) void k_scan(const int* __restrict__ deg, int* __restrict__ row,
                                               int* __restrict__ cursor, int N){
  __shared__ int buf[2][1024];
  __shared__ int carry;
  int t = threadIdx.x;
  if(t==0) carry=0;
  __syncthreads();
  for(int base=0; base<N; base+=1024){
    int i = base+t;
    int v = (i<N)? deg[i] : 0;
    int cur=0;
    buf[0][t]=v; __syncthreads();
    for(int off=1; off<1024; off<<=1){
      int val = buf[cur][t];
      if(t>=off) val += buf[cur][t-off];
      buf[cur^1][t]=val; __syncthreads();
      cur^=1;
    }
    if(i<N) row[i] = carry + buf[cur][t] - v;
    int tot = buf[cur][1023];
    __syncthreads();
    if(t==0) carry += tot;
    __syncthreads();
  }
  if(t==0) row[N]=carry;
  for(int i=t;i<N;i+=1024) cursor[i]=0;
}

__global__ void k_fill(const int* __restrict__ edst, const int* __restrict__ row,
                       int* __restrict__ cursor, int* __restrict__ perm, int E){
  int e = blockIdx.x*256 + threadIdx.x;
  if(e<E){
    int d = edst[e];
    int p = atomicAdd(&cursor[d], 1);
    perm[row[d]+p] = e;
  }
}

#define NB1 (17*8*64*8)
#define NB2 (2*8*64*8)
#define NW1 (16*64*8)
__global__ void k_prep(const float* __restrict__ W2a, const float* __restrict__ W2b,
                       const float* __restrict__ W1a, const float* __restrict__ W1b,
                       unsigned short* __restrict__ B1, unsigned short* __restrict__ B2,
                       unsigned short* __restrict__ W1p1, unsigned short* __restrict__ W1p2,
                       const TPTables* __restrict__ T){
  int i = blockIdx.x*256 + threadIdx.x;
  if(i < NB1){
    int s = i&7, lane = (i>>3)&63, ks = (i>>9)&7, ct = i>>12;
    int g = lane>>4;
    int k = ks*32 + g*4 + (s&3) + ((s>>2)<<4);
    int c = ct*16 + (lane&15);
    B1[i] = f2h(W2a[k*272+c]*0.0625f*T->alpha1[c]);
  } else if(i < NB1+NB2){
    int j = i - NB1;
    int s = j&7, lane = (j>>3)&63, ks = (j>>9)&7, ct = j>>12;
    int g = lane>>4;
    int k = ks*32 + g*4 + (s&3) + ((s>>2)<<4);
    int c = ct*16 + (lane&15);
    B2[j] = f2h(W2b[k*32+c]*0.0625f*T->alpha2[c]);
  } else if(i < NB1+NB2+NW1){
    int j = i - NB1 - NB2;
    int s = j&7, lane = (j>>3)&63, ct = j>>9;
    int g = lane>>4;
    int k = g*4 + (s&3) + ((s>>2)<<4);
    int c = ct*16 + (lane&15);
    W1p1[j] = (k<10)? f2h(W1a[k*256+c]*0.4472135954999579f) : (unsigned short)0;
  } else if(i < NB1+NB2+2*NW1){
    int j = i - NB1 - NB2 - NW1;
    int s = j&7, lane = (j>>3)&63, ct = j>>9;
    int g = lane>>4;
    int k = g*4 + (s&3) + ((s>>2)<<4);
    int c = ct*16 + (lane&15);
    W1p2[j] = (k<10)? f2h(W1b[k*256+c]*0.4472135954999579f) : (unsigned short)0;
  }
}

__global__ __launch_bounds__(256) void k_edge_pre(
    const float* __restrict__ pos, const int* __restrict__ esrc, const int* __restrict__ edst,
    const int* __restrict__ perm, float* __restrict__ x, int E){
  __shared__ float shs[256*17];
  __shared__ int dsts[256];
  int t = threadIdx.x;
  int idx = blockIdx.x*256 + t;
  int d = -1;
  if(idx<E){
    int e = perm[idx];
    int s = esrc[e]; d = edst[e];
    float ex=pos[3*d]-pos[3*s], ey=pos[3*d+1]-pos[3*s+1], ez=pos[3*d+2]-pos[3*s+2];
    float dd = sqrtf(ex*ex+ey*ey+ez*ez+1e-12f);
    sph16(ex/dd, ey/dd, ez/dd, &shs[t*17]);
  }
  dsts[t] = d;
  __syncthreads();
  bool leader = (d>=0) && (t==0 || dsts[t-1]!=d);
  if(leader){
    int len=1;
    while(t+len<256 && dsts[t+len]==d) len++;
    #pragma unroll
    for(int j=0;j<16;j++){
      float a=0.f;
      for(int k=0;k<len;k++) a += shs[(t+k)*17+j];
      atomicAdd(&x[(size_t)d*16+j], a);
    }
  }
}

// LDS (floats) k_fc1_tp1 (512 threads):
//   sh_t @0 [32][17] | x1_t @544 | emb_t @1088 -> 1632
//   Wt_h @1632 us[32][276] (8832us=4416f) -> 6048
//   AFh @6048: H-frags us[2][8][64][8]=8192us; P us[32][264]=8448us (4224f) -> 10272
//   S16 @10272 us[32][40]=1280us (640f) -> 10912
//   ef @10912 [32][65]=2080f -> 12992
#define F1_WT 1632
#define F1_AF 6048
#define F1_S  10272
#define F1_EF 10912
#define F1_TOT 12992
#define WST 276

__global__ __launch_bounds__(512,6) void k_fc1_tp1(
    const float* __restrict__ pos, const int* __restrict__ esrc, const int* __restrict__ edst,
    const int* __restrict__ perm,
    const unsigned short* __restrict__ W1p, const unsigned short* __restrict__ B1,
    const float* __restrict__ xnode, float* __restrict__ ef1,
    const TPTables* __restrict__ T, int E, float inv_nn)
{
  __shared__ __align__(16) float sm[F1_TOT];
  __shared__ int src_t[TILE], dst_t[TILE];
  float* sh_t  = sm;
  float* x1_t  = sm + 544;
  float* emb_t = sm + 1088;
  unsigned short* Wt_h = (unsigned short*)(sm + F1_WT);
  unsigned short* AFh  = (unsigned short*)(sm + F1_AF);
  unsigned short* S16h = (unsigned short*)(sm + F1_S);
  float* ef_h = sm + F1_EF;
  int t = threadIdx.x;
  int e0 = blockIdx.x*TILE;
  int nE = min(TILE, E-e0);
  int e = t>>4, g = t&15, w = t>>6, lane = t&63;
  int g2 = lane>>4, lr = lane&15;

  if(t<TILE){
    float embr[10];
    if(t<nE){
      int e2 = perm[e0+t];
      int s=esrc[e2], d=edst[e2];
      src_t[t]=s; dst_t[t]=d;
      float ex=pos[3*d]-pos[3*s], ey=pos[3*d+1]-pos[3*s+1], ez=pos[3*d+2]-pos[3*s+2];
      float dd=sqrtf(ex*ex+ey*ey+ez*ez+1e-12f);
      sph16(ex/dd,ey/dd,ez/dd, &sh_t[t*17]);
      radial10(dd, embr);
    } else {
      src_t[t]=0; dst_t[t]=-1;
      #pragma unroll
      for(int j=0;j<16;j++) sh_t[t*17+j]=0.f;
      #pragma unroll
      for(int b=0;b<10;b++) embr[b]=0.f;
    }
    #pragma unroll
    for(int b=0;b<10;b++) emb_t[t*17+b]=embr[b];
  }
  __syncthreads();
  x1_t[e*17+g] = xnode[(size_t)src_t[e]*16+g]*inv_nn;
  // ph1: H = relu(emb @ W1p) -> A-fragment-major LDS (sig-swizzled lane slots)
  {
    float af0[8], af1[8];
    #pragma unroll
    for(int s=0;s<8;s++){
      int k = g2*4 + (s&3) + ((s>>2)<<4);
      af0[s] = (k<10)? emb_t[lr*17+k] : 0.f;
      af1[s] = (k<10)? emb_t[(16+lr)*17+k] : 0.f;
    }
    union { f16x8 v; uint32_t w4[4]; } a0u, a1u;
    #pragma unroll
    for(int i=0;i<4;i++){
      a0u.w4[i] = (uint32_t)f2h(af0[2*i]) | ((uint32_t)f2h(af0[2*i+1])<<16);
      a1u.w4[i] = (uint32_t)f2h(af1[2*i]) | ((uint32_t)f2h(af1[2*i+1])<<16);
    }
    #pragma unroll
    for(int q=0;q<2;q++){
      int ct = w*2+q;
      f16x8 b = *(const f16x8*)(W1p + ((size_t)(ct*64+lane))*8);
      f32x4 z = {0.f,0.f,0.f,0.f};
      f32x4 c0 = __builtin_amdgcn_mfma_f32_16x16x32_f16(a0u.v, b, z, 0,0,0);
      f32x4 c1 = __builtin_amdgcn_mfma_f32_16x16x32_f16(a1u.v, b, z, 0,0,0);
      int ks = ct>>1, sp = (lr&3)|((ct&1)<<2);
      #pragma unroll
      for(int r=0;r<4;r++){
        int lnp = ((lr>>2)<<4) + (g2<<2) + r;
        int sl = sig(lnp);
        AFh[(ks*64+sl)*8+sp]     = f2h(fmaxf(c0[r],0.f));
        AFh[((8+ks)*64+sl)*8+sp] = f2h(fmaxf(c1[r],0.f));
      }
    }
  }
  __syncthreads();
  // ph2: W = H @ B1 (fp16 Wt, sig-swizzled A-frag reads)
  {
    int sl = sig(lane);
    for(int ct=w; ct<17; ct+=8){
      f32x4 acc0 = {0.f,0.f,0.f,0.f}, acc1 = {0.f,0.f,0.f,0.f};
      #pragma unroll
      for(int ks=0;ks<8;ks++){
        f16x8 b  = *(const f16x8*)(B1 + ((size_t)(ct*8+ks)*64 + lane)*8);
        f16x8 a0 = *(const f16x8*)(AFh + (ks*64+sl)*8);
        f16x8 a1 = *(const f16x8*)(AFh + ((8+ks)*64+sl)*8);
        acc0 = __builtin_amdgcn_mfma_f32_16x16x32_f16(a0, b, acc0, 0,0,0);
        acc1 = __builtin_amdgcn_mfma_f32_16x16x32_f16(a1, b, acc1, 0,0,0);
      }
      #pragma unroll
      for(int r=0;r<4;r++){
        Wt_h[(g2*4+r)*WST + ct*16+lr]    = f2h(acc0[r]);
        Wt_h[(16+g2*4+r)*WST + ct*16+lr] = f2h(acc1[r]);
      }
    }
  }
  __syncthreads();
  // ph3: outer products P[i][j] = x1[i]*sh[j]
  {
    float xv = x1_t[e*17+g];
    float shv[16];
    #pragma unroll
    for(int j=0;j<16;j++) shv[j]=sh_t[e*17+j];
    uint32_t* dst = (uint32_t*)AFh + e*132 + g*8;
    #pragma unroll
    for(int jp=0;jp<8;jp++)
      dst[jp] = (uint32_t)f2h(xv*shv[2*jp]) | ((uint32_t)f2h(xv*shv[2*jp+1])<<16);
  }
  __syncthreads();
  // ph4: branch-free cg contraction [40][16]
  {
    const uint2* cgt = (const uint2*)T->cg1p;
    #pragma unroll
    for(int p=0;p<3;p++){
      int slot = p*16+g;
      if(slot<40){
        float acc=0.f;
        #pragma unroll
        for(int q=0;q<16;q++){
          uint2 v = cgt[slot*16+q];
          acc += __uint_as_float(v.y) * h2f(AFh[e*264 + (v.x&0xff)]);
        }
        S16h[e*40+slot] = f2h(acc);
      }
    }
  }
  __syncthreads();
  // ph5: out phase
  float a0=0.f, a1=0.f, accB[3]={0.f,0.f,0.f}, accC[3]={0.f,0.f,0.f};
  {
    int grp = (g>=8)+(g>=12);
    int base = (grp==0)?0:((grp==1)?16:24);
    int ol = g*2 - base;
    #pragma unroll
    for(int p=0;p<4;p++){
      uint32_t v = T->tabA[grp*4+p];
      int w0 = v&0xffff, sb = v>>16;
      float Sv = h2f(S16h[e*40+sb]);
      uint32_t wp = *(const uint32_t*)(Wt_h + e*WST + w0 + ol);
      a0 += h2f((unsigned short)(wp&0xffff))*Sv;
      a1 += h2f((unsigned short)(wp>>16))*Sv;
    }
    #pragma unroll
    for(int p=0;p<6;p++){
      uint32_t v = T->tabB[p];
      int w0 = v&0xffff, sb = v>>16;
      float Wv = h2f(Wt_h[e*WST + w0 + g]);
      accB[0] += Wv*h2f(S16h[e*40+sb]);
      accB[1] += Wv*h2f(S16h[e*40+sb+1]);
      accB[2] += Wv*h2f(S16h[e*40+sb+2]);
    }
    #pragma unroll
    for(int p=0;p<3;p++){
      uint32_t v = T->tabC[p];
      int w0 = v&0xffff, sb = v>>16;
      float Wv = h2f(Wt_h[e*WST + w0 + g]);
      accC[0] += Wv*h2f(S16h[e*40+sb]);
      accC[1] += Wv*h2f(S16h[e*40+sb+1]);
      accC[2] += Wv*h2f(S16h[e*40+sb+2]);
    }
  }
  // two flush passes (no zero-fill: every (e,col) written exactly once;
  // tail edges produce zeros and are skipped via dst<0)
  #pragma unroll
  for(int h=0; h<2; h++){
    if(h==0){
      ef_h[e*65 + g*2]   = a0;
      ef_h[e*65 + g*2+1] = a1;
      #pragma unroll
      for(int k=0;k<3;k++){
        int b = g*3+k;
        if(b<32) ef_h[e*65 + 32+b] = accB[k];
      }
    } else {
      #pragma unroll
      for(int k=0;k<3;k++){
        int b = g*3+k;
        if(b>=32) ef_h[e*65 + (b-32)] = accB[k];
      }
      #pragma unroll
      for(int k=0;k<3;k++)
        ef_h[e*65 + 16 + g*3+k] = accC[k];
    }
    __syncthreads();
    if(t<64){
      int rank = h*64+t;
      int opos = rank<16? rank : rank<24? rank+16 : rank<32? rank+24 : rank+32;
      float acc=0.f;
      for(int e2=0;e2<TILE;e2++){
        int d = dst_t[e2];
        if(d>=0) acc += ef_h[e2*65+t];
        bool bnd = (e2==TILE-1) || (dst_t[e2+1]!=d);
        if(bnd){
          if(d>=0 && acc!=0.f) atomicAdd(&ef1[(size_t)d*160 + opos], acc);
          acc=0.f;
        }
      }
    }
    __syncthreads();
  }
}

__global__ void k_gate(const float* __restrict__ ef1, float* __restrict__ xg, int N, float inv_nn){
  int n = blockIdx.x*256+threadIdx.x;
  if(n>=N) return;
  const float* v = ef1 + (size_t)n*160;
  float* o = xg + (size_t)n*128;
  float g[32];
  #pragma unroll
  for(int i=0;i<16;i++) o[i] = fmaxf(v[i]*inv_nn, 0.f);
  #pragma unroll
  for(int i=0;i<16;i++) o[16+i] = tanhf(v[16+i]*inv_nn);
  #pragma unroll
  for(int i=0;i<8;i++) g[i]    = fmaxf(v[32+i]*inv_nn,0.f);
  #pragma unroll
  for(int i=0;i<8;i++) g[8+i]  = tanhf(v[40+i]*inv_nn);
  #pragma unroll
  for(int i=0;i<8;i++) g[16+i] = fmaxf(v[48+i]*inv_nn,0.f);
  #pragma unroll
  for(int i=0;i<8;i++) g[24+i] = tanhf(v[56+i]*inv_nn);
  #pragma unroll
  for(int u=0;u<32;u++){
    float gu = g[u];
    #pragma unroll
    for(int k=0;k<3;k++) o[32+u*3+k] = v[64+u*3+k]*inv_nn*gu;
  }
}

// LDS (floats) k_fc2_tp2 (512 threads):
//   sh @0 544 | emb @544 -> 1088 | xg @1088 [32][65] 2080 -> 3168
//   Wt @3168 f32[32][37] 1184 -> 4352
//   AF @4352 4096f (S_l f32 [32][33]=1056 aliases) -> 8448 | bins @8448 16
#define F2_WT 3168
#define F2_AF 4352
#define F2_BINS 8448
#define F2_TOT 8464

__global__ __launch_bounds__(512,6) void k_fc2_tp2(
    const float* __restrict__ pos, const int* __restrict__ esrc, const int* __restrict__ edst,
    const int* __restrict__ perm, const int* __restrict__ batch,
    const unsigned short* __restrict__ W1p, const unsigned short* __restrict__ B2,
    const float* __restrict__ xg, float* __restrict__ out,
    const TPTables* __restrict__ T, int E, float out_scale, int G)
{
  __shared__ __align__(16) float sm[F2_TOT];
  __shared__ int src_t[TILE], dst_t[TILE], g_t[TILE];
  float* sh_t  = sm;
  float* emb_t = sm + 544;
  float* xg_t  = sm + 1088;
  float* Wt    = sm + F2_WT;
  unsigned short* AFh = (unsigned short*)(sm + F2_AF);
  float* S_l  = sm + F2_AF;
  float* bins = sm + F2_BINS;
  int t = threadIdx.x;
  int e0 = blockIdx.x*TILE;
  int nE = min(TILE, E-e0);
  int e = t>>4, g = t&15, w = t>>6, lane = t&63;
  int g2 = lane>>4, lr = lane&15;

  if(t<TILE){
    float embr[10];
    if(t<nE){
      int e2 = perm[e0+t];
      int s=esrc[e2], d=edst[e2];
      src_t[t]=s; dst_t[t]=d; g_t[t]=batch[d];
      float ex=pos[3*d]-pos[3*s], ey=pos[3*d+1]-pos[3*s+1], ez=pos[3*d+2]-pos[3*s+2];
      float dd=sqrtf(ex*ex+ey*ey+ez*ez+1e-12f);
      sph16(ex/dd,ey/dd,ez/dd, &sh_t[t*17]);
      radial10(dd, embr);
    } else {
      src_t[t]=0; dst_t[t]=-1; g_t[t]=0;
      #pragma unroll
      for(int j=0;j<16;j++) sh_t[t*17+j]=0.f;
      #pragma unroll
      for(int b=0;b<10;b++) embr[b]=0.f;
    }
    #pragma unroll
    for(int b=0;b<10;b++) emb_t[t*17+b]=embr[b];
  } else if(t<TILE+16){
    bins[t-TILE]=0.f;
  }
  __syncthreads();
  #pragma unroll
  for(int rep=0;rep<4;rep++){
    int j = g + rep*16;
    xg_t[e*65+j] = xg[(size_t)src_t[e]*128 + (j<16? j : j+16)];
  }
  {
    float af0[8], af1[8];
    #pragma unroll
    for(int s=0;s<8;s++){
      int k = g2*4 + (s&3) + ((s>>2)<<4);
      af0[s] = (k<10)? emb_t[lr*17+k] : 0.f;
      af1[s] = (k<10)? emb_t[(16+lr)*17+k] : 0.f;
    }
    union { f16x8 v; uint32_t w4[4]; } a0u, a1u;
    #pragma unroll
    for(int i=0;i<4;i++){
      a0u.w4[i] = (uint32_t)f2h(af0[2*i]) | ((uint32_t)f2h(af0[2*i+1])<<16);
      a1u.w4[i] = (uint32_t)f2h(af1[2*i]) | ((uint32_t)f2h(af1[2*i+1])<<16);
    }
    #pragma unroll
    for(int q=0;q<2;q++){
      int ct = w*2+q;
      f16x8 b = *(const f16x8*)(W1p + ((size_t)(ct*64+lane))*8);
      f32x4 z = {0.f,0.f,0.f,0.f};
      f32x4 c0 = __builtin_amdgcn_mfma_f32_16x16x32_f16(a0u.v, b, z, 0,0,0);
      f32x4 c1 = __builtin_amdgcn_mfma_f32_16x16x32_f16(a1u.v, b, z, 0,0,0);
      int ks = ct>>1, sp = (lr&3)|((ct&1)<<2);
      #pragma unroll
      for(int r=0;r<4;r++){
        int lnp = ((lr>>2)<<4) + (g2<<2) + r;
        int sl = sig(lnp);
        AFh[(ks*64+sl)*8+sp]     = f2h(fmaxf(c0[r],0.f));
        AFh[((8+ks)*64+sl)*8+sp] = f2h(fmaxf(c1[r],0.f));
      }
    }
  }
  __syncthreads();
  {
    if(w<2){
      int ct = w;
      int sl = sig(lane);
      f32x4 acc0 = {0.f,0.f,0.f,0.f}, acc1 = {0.f,0.f,0.f,0.f};
      #pragma unroll
      for(int ks=0;ks<8;ks++){
        f16x8 b  = *(const f16x8*)(B2 + ((size_t)(ct*8+ks)*64 + lane)*8);
        f16x8 a0 = *(const f16x8*)(AFh + (ks*64+sl)*8);
        f16x8 a1 = *(const f16x8*)(AFh + ((8+ks)*64+sl)*8);
        acc0 = __builtin_amdgcn_mfma_f32_16x16x32_f16(a0, b, acc0, 0,0,0);
        acc1 = __builtin_amdgcn_mfma_f32_16x16x32_f16(a1, b, acc1, 0,0,0);
      }
      #pragma unroll
      for(int r=0;r<4;r++){
        Wt[(g2*4+r)*37 + ct*16+lr]    = acc0[r];
        Wt[(16+g2*4+r)*37 + ct*16+lr] = acc1[r];
      }
    }
  }
  __syncthreads();
  {
    const uint2* cgt = (const uint2*)T->cg2p;
    #pragma unroll
    for(int p=0;p<2;p++){
      int slot = p*16 + g;
      float acc=0.f;
      #pragma unroll
      for(int q=0;q<4;q++){
        uint2 v = cgt[slot*4+q];
        acc += __uint_as_float(v.y) * xg_t[e*65+(v.x&0xff)] * sh_t[e*17+((v.x>>8)&0xff)];
      }
      S_l[e*33+slot]=acc;
    }
  }
  __syncthreads();
  {
    uint32_t u0 = T->out2p[2*g], u1 = T->out2p[2*g+1];
    float v = Wt[e*37+(u0&0xffff)] * S_l[e*33+(u0>>16)]
            + Wt[e*37+(u1&0xffff)] * S_l[e*33+(u1>>16)];
    #pragma unroll
    for(int m=1;m<16;m<<=1) v += __shfl_xor(v, m, 64);
    if(g==0 && e<nE) atomicAdd(&bins[g_t[e]], v);
  }
  __syncthreads();
  if(t<G) atomicAdd(&out[t], bins[t]*out_scale);
}

// ---------------- launch ----------------
extern "C" void kernel_launch(void* const* d_in, const int* in_sizes, int n_in,
                              void* d_out, int out_size, void* d_ws, size_t ws_size,
                              hipStream_t stream) {
  const float* pos  = (const float*)d_in[0];
  const float* w11  = (const float*)d_in[1];
  const float* w12  = (const float*)d_in[2];
  const float* w21  = (const float*)d_in[3];
  const float* w22  = (const float*)d_in[4];
  const int*   esrc = (const int*)d_in[5];
  const int*   edst = (const int*)d_in[6];
  const int*   batch= (const int*)d_in[7];
  int E = in_sizes[5];
  int N = in_sizes[0]/3;
  int G = out_size;

  double nn = std::sqrt((double)E/(double)N);
  float inv_nn    = (float)(1.0/nn);
  float out_scale = (float)(1.0/(nn*std::sqrt((double)N)));

  float* ws = (float*)d_ws;
  float* x   = ws;
  float* ef1 = x   + (size_t)N*16;
  float* xg  = ef1 + (size_t)N*160;
  TPTables* dT = (TPTables*)(xg + (size_t)N*128);
  unsigned short* B1   = (unsigned short*)(((char*)dT) + ((sizeof(TPTables)+255)&~(size_t)255));
  unsigned short* B2   = B1 + NB1;
  unsigned short* W1p1 = B2 + NB2;
  unsigned short* W1p2 = W1p1 + NW1;
  int* deg    = (int*)(W1p2 + NW1);
  int* row    = deg + N;
  int* cursor = row + (N+1);
  int* perm   = cursor + N;

  static TPTables hT;
  build_tables(hT);
  hipMemcpyAsync(dT, &hT, sizeof(TPTables), hipMemcpyHostToDevice, stream);

  size_t nz = (size_t)N*16 + (size_t)N*160 + G + N;
  int zgrid = (int)((nz+255)/256); if(zgrid>2048) zgrid=2048;
  k_zero<<<zgrid,256,0,stream>>>(x, (size_t)N*16, ef1, (size_t)N*160, (float*)d_out, (size_t)G, deg, (size_t)N);
  k_deg<<<(E+255)/256,256,0,stream>>>(edst, deg, E);
  k_scan<<<1,1024,0,stream>>>(deg, row, cursor, N);
  k_fill<<<(E+255)/256,256,0,stream>>>(edst, row, cursor, perm, E);
  k_prep<<<(NB1+NB2+2*NW1+255)/256,256,0,stream>>>(w12, w22, w11, w21, B1, B2, W1p1, W1p2, dT);
  k_edge_pre<<<(E+255)/256,256,0,stream>>>(pos, esrc, edst, perm, x, E);
  k_fc1_tp1<<<(E+TILE-1)/TILE,512,0,stream>>>(pos, esrc, edst, perm, W1p1, B1, x, ef1, dT, E, inv_nn);
  k_gate<<<(N+255)/256,256,0,stream>>>(ef1, xg, N, inv_nn);
  k_fc2_tp2<<<(E+TILE-1)/TILE,512,0,stream>>>(pos, esrc, edst, perm, batch, W1p2, B2, xg,
                                              (float*)d_out, dT, E, out_scale, G);
}

// Round 9
// 1087.857 us; speedup vs baseline: 1.0480x; 1.0480x over previous
//
#include <hip/hip_runtime.h>
#include <cmath>
#include <cstdint>
#include <cstring>
#include <cstdlib>
#include <vector>
#include <algorithm>
#include <complex>

#define TILE 32

typedef __attribute__((ext_vector_type(8))) _Float16 f16x8;
typedef __attribute__((ext_vector_type(4))) float f32x4;

// ------------------------------------------------------------------
// TP tables: branch-free cg [40][16]; structural path tables for the
// out phase (fan 4/6/3 per class); alphas folded into W2.
// ------------------------------------------------------------------
struct TPTables {
  uint32_t cg1p[40*16*2];   // [slot][16] uint2 {prodidx(i*16+j), coefbits}
  uint32_t tabA[12];        // [grp(i3=0,2,4)][4 paths] = w0 | sbase<<16
  uint32_t tabB[6];         // i3=6 paths
  uint32_t tabC[3];         // i3=7 paths
  uint32_t cg2p[32*4*2];    // uint2 {i | j<<8, coefbits}
  uint32_t out2p[32];       // widx | s<<16
  float alpha1[272];
  float alpha2[32];
};

static double factd(int n){ double r=1; for(int i=2;i<=n;i++) r*=(double)i; return r; }

static double cg_complex(int j1,int m1,int j2,int m2,int j3,int m3){
  if(m1+m2!=m3) return 0.0;
  double pref = std::sqrt((2*j3+1)*factd(j3+j1-j2)*factd(j3-j1+j2)*factd(j1+j2-j3)/factd(j1+j2+j3+1));
  pref *= std::sqrt(factd(j3+m3)*factd(j3-m3)*factd(j1-m1)*factd(j1+m1)*factd(j2-m2)*factd(j2+m2));
  double s=0.0;
  for(int k=0;k<=j1+j2-j3;k++){
    int dd[6] = {k, j1+j2-j3-k, j1-m1-k, j2+m2-k, j3-j2+m1+k, j3-j1-m2+k};
    bool ok=true; double prod=1.0;
    for(int t=0;t<6;t++){ if(dd[t]<0){ok=false;break;} prod*=factd(dd[t]); }
    if(!ok) continue;
    s += ((k&1)?-1.0:1.0)/prod;
  }
  return pref*s;
}

typedef std::complex<double> cd;
static void real_U(int l, cd* U){
  int n = 2*l+1;
  for(int i=0;i<n*n;i++) U[i]=cd(0,0);
  U[l*n+l] = cd(1,0);
  for(int m=1;m<=l;m++){
    double sgn = (m&1)? -1.0 : 1.0;
    double is2 = 1.0/std::sqrt(2.0);
    U[(l+m)*n + (l+m)] = cd(sgn*is2,0);
    U[(l+m)*n + (l-m)] = cd(is2,0);
    U[(l-m)*n + (l+m)] = cd(0,-sgn*is2);
    U[(l-m)*n + (l-m)] = cd(0,is2);
  }
}

static void real_cg_h(int l1,int l2,int l3, double* out){
  int n1=2*l1+1,n2=2*l2+1,n3=2*l3+1;
  std::vector<cd> C(n1*n2*n3);
  for(int a=-l1;a<=l1;a++)for(int b=-l2;b<=l2;b++)for(int c=-l3;c<=l3;c++)
    C[(size_t)((a+l1)*n2+(b+l2))*n3+(c+l3)] = cd(cg_complex(l1,a,l2,b,l3,c),0);
  std::vector<cd> U1(n1*n1),U2(n2*n2),U3(n3*n3);
  real_U(l1,U1.data()); real_U(l2,U2.data()); real_U(l3,U3.data());
  std::vector<cd> T((size_t)n1*n2*n3, cd(0,0));
  for(int i=0;i<n1;i++)for(int j=0;j<n2;j++)for(int k=0;k<n3;k++){
    cd acc(0,0);
    for(int a=0;a<n1;a++){ cd u1=U1[i*n1+a]; if(u1==cd(0,0)) continue;
      for(int b=0;b<n2;b++){ cd u2=U2[j*n2+b]; if(u2==cd(0,0)) continue;
        for(int c=0;c<n3;c++){ cd u3=std::conj(U3[k*n3+c]); if(u3==cd(0,0)) continue;
          acc += u1*u2*u3*C[(size_t)(a*n2+b)*n3+c];
        } } }
    T[(size_t)(i*n2+j)*n3+k]=acc;
  }
  double sr=0, si=0;
  for(auto&z:T){ sr += std::fabs(z.real()); si += std::fabs(z.imag()); }
  int tot=n1*n2*n3;
  std::vector<double> R(tot);
  for(int i=0;i<tot;i++) R[i] = (sr>=si)? T[i].real() : T[i].imag();
  double nrm=0; for(double v:R) nrm += v*v; nrm = std::sqrt(nrm);
  for(int i=0;i<tot;i++) out[i] = R[i]/nrm;
}

struct HIrr{int m,l,p;};
static int map_id(int i){return i;}
static int map_gate(int i){return (i<16)? i : i-16;}

static void build_one(const std::vector<HIrr>& ir1, const std::vector<HIrr>& ir2,
                      const std::vector<HIrr>& ir3, int (*map1)(int),
                      std::vector<uint32_t>& cg_pk, std::vector<float>& cg_c,
                      std::vector<uint32_t>& out_pk, std::vector<float>& out_c)
{
  int n1=(int)ir1.size(), n2=(int)ir2.size(), n3=(int)ir3.size();
  std::vector<int> s1(n1), s2(n2), s3(n3);
  { int o=0; for(int i=0;i<n1;i++){ s1[i]=o; o+=ir1[i].m*(2*ir1[i].l+1);} }
  { int o=0; for(int i=0;i<n2;i++){ s2[i]=o; o+=ir2[i].m*(2*ir2[i].l+1);} }
  { int o=0; for(int i=0;i<n3;i++){ s3[i]=o; o+=ir3[i].m*(2*ir3[i].l+1);} }
  struct Inst{int i1,i2,i3,w0;};
  std::vector<Inst> insts; int woff=0;
  for(int i1=0;i1<n1;i1++)for(int i2=0;i2<n2;i2++)for(int i3=0;i3<n3;i3++){
    const HIrr&A=ir1[i1];const HIrr&B=ir2[i2];const HIrr&C=ir3[i3];
    int dl = A.l-B.l; if(dl<0) dl=-dl;
    if(A.p*B.p==C.p && dl<=C.l && C.l<=A.l+B.l){
      insts.push_back({i1,i2,i3,woff}); woff += A.m*B.m*C.m;
    }
  }
  std::vector<int> fan(n3,0);
  for(auto&P:insts) fan[P.i3] += ir1[P.i1].m*ir2[P.i2].m;
  int sbase=0;
  for(auto&P:insts){
    const HIrr&A=ir1[P.i1];const HIrr&B=ir2[P.i2];const HIrr&C=ir3[P.i3];
    int d1=2*A.l+1,d2=2*B.l+1,d3=2*C.l+1;
    double cg[343];
    real_cg_h(A.l,B.l,C.l,cg);
    double alpha = std::sqrt((double)d3/(double)fan[P.i3]);
    for(int u=0;u<A.m;u++)for(int v=0;v<B.m;v++){
      for(int k=0;k<d3;k++)
        for(int i=0;i<d1;i++)for(int j=0;j<d2;j++){
          double c = cg[(i*d2+j)*d3+k];
          if(std::fabs(c)<1e-8) continue;
          int iabs = map1(s1[P.i1]+u*d1+i);
          int jabs = s2[P.i2]+v*d2+j;
          cg_pk.push_back((uint32_t)iabs | ((uint32_t)jabs<<8) | ((uint32_t)(sbase+k)<<16));
          cg_c.push_back((float)c);
        }
      for(int w=0;w<C.m;w++)for(int k=0;k<d3;k++){
        out_pk.push_back((uint32_t)(s3[P.i3]+w*d3+k) | ((uint32_t)(P.w0+(u*B.m+v)*C.m+w)<<8) | ((uint32_t)(sbase+k)<<20));
        out_c.push_back((float)alpha);
      }
      sbase += d3;
    }
  }
}

static uint32_t fbits(float f){ uint32_t u; memcpy(&u,&f,4); return u; }

static void build_tables(TPTables& T){
  std::vector<HIrr> IR_SH   ={{1,0,1},{1,1,-1},{1,2,1},{1,3,-1}};
  std::vector<HIrr> GATE_IN ={{16,0,1},{16,0,-1},{8,0,1},{8,0,-1},{8,0,1},{8,0,-1},{16,1,-1},{16,1,1}};
  std::vector<HIrr> GATE_OUT={{16,0,1},{16,0,-1},{16,1,-1},{16,1,1}};
  std::vector<HIrr> IR_OUT  ={{1,0,1}};
  std::vector<uint32_t> cg1,o1,cg2,o2; std::vector<float> cg1c,o1c,cg2c,o2c;
  build_one(IR_SH,IR_SH,GATE_IN,map_id,cg1,cg1c,o1,o1c);
  build_one(GATE_OUT,IR_SH,IR_OUT,map_gate,cg2,cg2c,o2,o2c);
  memset(&T,0,sizeof(T));
  {
    int cnt[40]; memset(cnt,0,sizeof(cnt));
    for(size_t idx=0; idx<cg1.size(); ++idx){
      int i = cg1[idx]&0xff, j=(cg1[idx]>>8)&0xff, s=(int)(cg1[idx]>>16);
      uint32_t pidx = (uint32_t)(i*16+j);
      if(s<40 && cnt[s]<16){
        T.cg1p[(s*16+cnt[s])*2]   = pidx;
        T.cg1p[(s*16+cnt[s])*2+1] = fbits(cg1c[idx]);
        cnt[s]++;
      }
    }
  }
  {
    int GIl[8]={0,0,0,0,0,0,1,1}, GIp[8]={1,-1,1,-1,1,-1,-1,1}, GIm[8]={16,16,8,8,8,8,16,16};
    int SHl[4]={0,1,2,3}, SHp[4]={1,-1,1,-1};
    int w0=0, sb=0, nA0=0,nA1=0,nA2=0,nB=0,nC=0;
    for(int i1=0;i1<4;i1++)for(int i2=0;i2<4;i2++)for(int i3=0;i3<8;i3++){
      int dl=SHl[i1]-SHl[i2]; if(dl<0) dl=-dl;
      if(SHp[i1]*SHp[i2]==GIp[i3] && dl<=GIl[i3] && GIl[i3]<=SHl[i1]+SHl[i2]){
        uint32_t ent = (uint32_t)w0 | ((uint32_t)sb<<16);
        if(i3==0 && nA0<4) T.tabA[nA0++] = ent;
        else if(i3==2 && nA1<4) T.tabA[4+nA1++] = ent;
        else if(i3==4 && nA2<4) T.tabA[8+nA2++] = ent;
        else if(i3==6 && nB<6) T.tabB[nB++] = ent;
        else if(i3==7 && nC<3) T.tabC[nC++] = ent;
        w0 += GIm[i3];
        sb += 2*GIl[i3]+1;
      }
    }
  }
  for(size_t idx=0; idx<o1.size(); ++idx){
    int widx = (o1[idx]>>8)&0xfff;
    if(widx<272) T.alpha1[widx] = o1c[idx];
  }
  {
    int cnt[32]; memset(cnt,0,sizeof(cnt));
    for(size_t idx=0; idx<cg2.size(); ++idx){
      int s = (int)(cg2[idx]>>16);
      if(s<32 && cnt[s]<4){
        T.cg2p[(s*4+cnt[s])*2]   = cg2[idx]&0xFFFF;
        T.cg2p[(s*4+cnt[s])*2+1] = fbits(cg2c[idx]);
        cnt[s]++;
      }
    }
  }
  for(size_t idx=0; idx<o2.size() && idx<32; ++idx){
    int widx = (o2[idx]>>8)&0xfff;
    int s    = (int)(o2[idx]>>20);
    T.out2p[idx] = (uint32_t)widx | ((uint32_t)s<<16);
    if(widx<32) T.alpha2[widx] = o2c[idx];
  }
}

// ---------------- device helpers ----------------
__device__ __forceinline__ unsigned short f2h(float f){
  _Float16 h = (_Float16)f;
  unsigned short u; __builtin_memcpy(&u, &h, 2); return u;
}
__device__ __forceinline__ float h2f(unsigned short u){
  _Float16 h; __builtin_memcpy(&h, &u, 2); return (float)h;
}
// bank-spread involution on 6-bit slot ids: low3 ^= high3.
// Reads (8 consecutive lanes, bits0-2 vary): sig mod 8 = lane mod 8 ^ const -> conflict-free.
// Stores (bits2-5 vary, bits0-1 fixed): sig mod 8 covers all 8 cells -> ~4-way (was 16-way).
__device__ __forceinline__ int sig(int x){ return x ^ (x>>3); }

__device__ __forceinline__ void sph16(float x,float y,float z,float* sh){
  float x2=x*x, y2=y*y, z2=z*z;
  const float SQ3=1.7320508075688772f, SQ5=2.23606797749979f, SQ7=2.6457513110645907f;
  const float SQ15=3.872983346207417f, SQ42=6.48074069840786f, SQ70=8.366600265340756f, SQ105=10.246950765959598f;
  sh[0]=1.f;
  sh[1]=SQ3*y;  sh[2]=SQ3*z;  sh[3]=SQ3*x;
  sh[4]=SQ15*x*y; sh[5]=SQ15*y*z; sh[6]=0.5f*SQ5*(3.f*z2-1.f); sh[7]=SQ15*x*z; sh[8]=0.5f*SQ15*(x2-y2);
  sh[9]=0.25f*SQ70*y*(3.f*x2-y2); sh[10]=SQ105*x*y*z; sh[11]=0.25f*SQ42*y*(5.f*z2-1.f);
  sh[12]=0.5f*SQ7*z*(5.f*z2-3.f); sh[13]=0.25f*SQ42*x*(5.f*z2-1.f);
  sh[14]=0.5f*SQ105*z*(x2-y2);    sh[15]=0.25f*SQ70*x*(x2-3.f*y2);
}

__device__ __forceinline__ void radial10(float d, float* emb){
  const float step = 0.2909090909090909f;
  #pragma unroll
  for(int b=0;b<10;b++){
    float c = step*(float)(b+1);
    float u = (d-c)/step;
    float u2 = u*u;
    float f = 0.f;
    if(u2<1.f) f = 1.14136f*__expf(-u2/fmaxf(1.f-u2,1e-6f));
    emb[b] = f*3.1622776601683795f;
  }
}

// ---------------- kernels ----------------
__global__ void k_zero(float* a, size_t na, float* b, size_t nb, float* c, size_t nc,
                       int* d, size_t nd){
  size_t total = na+nb+nc+nd;
  for(size_t i = (size_t)blockIdx.x*blockDim.x+threadIdx.x; i<total; i += (size_t)gridDim.x*blockDim.x){
    if(i<na) a[i]=0.f;
    else if(i<na+nb) b[i-na]=0.f;
    else if(i<na+nb+nc) c[i-na-nb]=0.f;
    else d[i-na-nb-nc]=0;
  }
}

__global__ void k_deg(const int* __restrict__ edst, int* __restrict__ deg, int E){
  int e = blockIdx.x*256 + threadIdx.x;
  if(e<E) atomicAdd(&deg[edst[e]], 1);
}

__global__ __launch_bounds__(1024) void k_scan(const int* __restrict__ deg, int* __restrict__ row,
                                               int* __restrict__ cursor, int N){
  __shared__ int buf[2][1024];
  __shared__ int carry;
  int t = threadIdx.x;
  if(t==0) carry=0;
  __syncthreads();
  for(int base=0; base<N; base+=1024){
    int i = base+t;
    int v = (i<N)? deg[i] : 0;
    int cur=0;
    buf[0][t]=v; __syncthreads();
    for(int off=1; off<1024; off<<=1){
      int val = buf[cur][t];
      if(t>=off) val += buf[cur][t-off];
      buf[cur^1][t]=val; __syncthreads();
      cur^=1;
    }
    if(i<N) row[i] = carry + buf[cur][t] - v;
    int tot = buf[cur][1023];
    __syncthreads();
    if(t==0) carry += tot;
    __syncthreads();
  }
  if(t==0) row[N]=carry;
  for(int i=t;i<N;i+=1024) cursor[i]=0;
}

__global__ void k_fill(const int* __restrict__ edst, const int* __restrict__ row,
                       int* __restrict__ cursor, int* __restrict__ perm, int E){
  int e = blockIdx.x*256 + threadIdx.x;
  if(e<E){
    int d = edst[e];
    int p = atomicAdd(&cursor[d], 1);
    perm[row[d]+p] = e;
  }
}

#define NB1 (17*8*64*8)
#define NB2 (2*8*64*8)
#define NW1 (16*64*8)
__global__ void k_prep(const float* __restrict__ W2a, const float* __restrict__ W2b,
                       const float* __restrict__ W1a, const float* __restrict__ W1b,
                       unsigned short* __restrict__ B1, unsigned short* __restrict__ B2,
                       unsigned short* __restrict__ W1p1, unsigned short* __restrict__ W1p2,
                       const TPTables* __restrict__ T){
  int i = blockIdx.x*256 + threadIdx.x;
  if(i < NB1){
    int s = i&7, lane = (i>>3)&63, ks = (i>>9)&7, ct = i>>12;
    int g = lane>>4;
    int k = ks*32 + g*4 + (s&3) + ((s>>2)<<4);
    int c = ct*16 + (lane&15);
    B1[i] = f2h(W2a[k*272+c]*0.0625f*T->alpha1[c]);
  } else if(i < NB1+NB2){
    int j = i - NB1;
    int s = j&7, lane = (j>>3)&63, ks = (j>>9)&7, ct = j>>12;
    int g = lane>>4;
    int k = ks*32 + g*4 + (s&3) + ((s>>2)<<4);
    int c = ct*16 + (lane&15);
    B2[j] = f2h(W2b[k*32+c]*0.0625f*T->alpha2[c]);
  } else if(i < NB1+NB2+NW1){
    int j = i - NB1 - NB2;
    int s = j&7, lane = (j>>3)&63, ct = j>>9;
    int g = lane>>4;
    int k = g*4 + (s&3) + ((s>>2)<<4);
    int c = ct*16 + (lane&15);
    W1p1[j] = (k<10)? f2h(W1a[k*256+c]*0.4472135954999579f) : (unsigned short)0;
  } else if(i < NB1+NB2+2*NW1){
    int j = i - NB1 - NB2 - NW1;
    int s = j&7, lane = (j>>3)&63, ct = j>>9;
    int g = lane>>4;
    int k = g*4 + (s&3) + ((s>>2)<<4);
    int c = ct*16 + (lane&15);
    W1p2[j] = (k<10)? f2h(W1b[k*256+c]*0.4472135954999579f) : (unsigned short)0;
  }
}

__global__ __launch_bounds__(256) void k_edge_pre(
    const float* __restrict__ pos, const int* __restrict__ esrc, const int* __restrict__ edst,
    const int* __restrict__ perm, float* __restrict__ x, int E){
  __shared__ float shs[256*17];
  __shared__ int dsts[256];
  int t = threadIdx.x;
  int idx = blockIdx.x*256 + t;
  int d = -1;
  if(idx<E){
    int e = perm[idx];
    int s = esrc[e]; d = edst[e];
    float ex=pos[3*d]-pos[3*s], ey=pos[3*d+1]-pos[3*s+1], ez=pos[3*d+2]-pos[3*s+2];
    float dd = sqrtf(ex*ex+ey*ey+ez*ez+1e-12f);
    sph16(ex/dd, ey/dd, ez/dd, &shs[t*17]);
  }
  dsts[t] = d;
  __syncthreads();
  bool leader = (d>=0) && (t==0 || dsts[t-1]!=d);
  if(leader){
    int len=1;
    while(t+len<256 && dsts[t+len]==d) len++;
    #pragma unroll
    for(int j=0;j<16;j++){
      float a=0.f;
      for(int k=0;k<len;k++) a += shs[(t+k)*17+j];
      atomicAdd(&x[(size_t)d*16+j], a);
    }
  }
}

// LDS (floats) k_fc1_tp1 (512 threads):
//   sh_t @0 [32][17] | x1_t @544 | emb_t @1088 -> 1632
//   Wt_h @1632 us[32][276] (8832us=4416f) -> 6048
//   AFh @6048: H-frags us[2][8][64][8]=8192us; P us[32][264]=8448us (4224f) -> 10272
//   S16 @10272 us[32][40]=1280us (640f) -> 10912
//   ef @10912 [32][65]=2080f -> 12992
#define F1_WT 1632
#define F1_AF 6048
#define F1_S  10272
#define F1_EF 10912
#define F1_TOT 12992
#define WST 276

__global__ __launch_bounds__(512,6) void k_fc1_tp1(
    const float* __restrict__ pos, const int* __restrict__ esrc, const int* __restrict__ edst,
    const int* __restrict__ perm,
    const unsigned short* __restrict__ W1p, const unsigned short* __restrict__ B1,
    const float* __restrict__ xnode, float* __restrict__ ef1,
    const TPTables* __restrict__ T, int E, float inv_nn)
{
  __shared__ __align__(16) float sm[F1_TOT];
  __shared__ int src_t[TILE], dst_t[TILE];
  float* sh_t  = sm;
  float* x1_t  = sm + 544;
  float* emb_t = sm + 1088;
  unsigned short* Wt_h = (unsigned short*)(sm + F1_WT);
  unsigned short* AFh  = (unsigned short*)(sm + F1_AF);
  unsigned short* S16h = (unsigned short*)(sm + F1_S);
  float* ef_h = sm + F1_EF;
  int t = threadIdx.x;
  int e0 = blockIdx.x*TILE;
  int nE = min(TILE, E-e0);
  int e = t>>4, g = t&15, w = t>>6, lane = t&63;
  int g2 = lane>>4, lr = lane&15;

  if(t<TILE){
    float embr[10];
    if(t<nE){
      int e2 = perm[e0+t];
      int s=esrc[e2], d=edst[e2];
      src_t[t]=s; dst_t[t]=d;
      float ex=pos[3*d]-pos[3*s], ey=pos[3*d+1]-pos[3*s+1], ez=pos[3*d+2]-pos[3*s+2];
      float dd=sqrtf(ex*ex+ey*ey+ez*ez+1e-12f);
      sph16(ex/dd,ey/dd,ez/dd, &sh_t[t*17]);
      radial10(dd, embr);
    } else {
      src_t[t]=0; dst_t[t]=-1;
      #pragma unroll
      for(int j=0;j<16;j++) sh_t[t*17+j]=0.f;
      #pragma unroll
      for(int b=0;b<10;b++) embr[b]=0.f;
    }
    #pragma unroll
    for(int b=0;b<10;b++) emb_t[t*17+b]=embr[b];
  }
  __syncthreads();
  x1_t[e*17+g] = xnode[(size_t)src_t[e]*16+g]*inv_nn;
  // ph1: H = relu(emb @ W1p) -> A-fragment-major LDS (sig-swizzled slots)
  {
    float af0[8], af1[8];
    #pragma unroll
    for(int s=0;s<8;s++){
      int k = g2*4 + (s&3) + ((s>>2)<<4);
      af0[s] = (k<10)? emb_t[lr*17+k] : 0.f;
      af1[s] = (k<10)? emb_t[(16+lr)*17+k] : 0.f;
    }
    union { f16x8 v; uint32_t w4[4]; } a0u, a1u;
    #pragma unroll
    for(int i=0;i<4;i++){
      a0u.w4[i] = (uint32_t)f2h(af0[2*i]) | ((uint32_t)f2h(af0[2*i+1])<<16);
      a1u.w4[i] = (uint32_t)f2h(af1[2*i]) | ((uint32_t)f2h(af1[2*i+1])<<16);
    }
    #pragma unroll
    for(int q=0;q<2;q++){
      int ct = w*2+q;
      f16x8 b = *(const f16x8*)(W1p + ((size_t)(ct*64+lane))*8);
      f32x4 z = {0.f,0.f,0.f,0.f};
      f32x4 c0 = __builtin_amdgcn_mfma_f32_16x16x32_f16(a0u.v, b, z, 0,0,0);
      f32x4 c1 = __builtin_amdgcn_mfma_f32_16x16x32_f16(a1u.v, b, z, 0,0,0);
      int ks = ct>>1, sp = (lr&3)|((ct&1)<<2);
      #pragma unroll
      for(int r=0;r<4;r++){
        int lnp = ((lr>>2)<<4) + (g2<<2) + r;
        int sl = sig(lnp);
        AFh[(ks*64+sl)*8+sp]     = f2h(fmaxf(c0[r],0.f));
        AFh[((8+ks)*64+sl)*8+sp] = f2h(fmaxf(c1[r],0.f));
      }
    }
  }
  __syncthreads();
  // ph2: W = H @ B1 (fp16 Wt, sig-swizzled A-frag reads)
  {
    int sl = sig(lane);
    for(int ct=w; ct<17; ct+=8){
      f32x4 acc0 = {0.f,0.f,0.f,0.f}, acc1 = {0.f,0.f,0.f,0.f};
      #pragma unroll
      for(int ks=0;ks<8;ks++){
        f16x8 b  = *(const f16x8*)(B1 + ((size_t)(ct*8+ks)*64 + lane)*8);
        f16x8 a0 = *(const f16x8*)(AFh + (ks*64+sl)*8);
        f16x8 a1 = *(const f16x8*)(AFh + ((8+ks)*64+sl)*8);
        acc0 = __builtin_amdgcn_mfma_f32_16x16x32_f16(a0, b, acc0, 0,0,0);
        acc1 = __builtin_amdgcn_mfma_f32_16x16x32_f16(a1, b, acc1, 0,0,0);
      }
      #pragma unroll
      for(int r=0;r<4;r++){
        Wt_h[(g2*4+r)*WST + ct*16+lr]    = f2h(acc0[r]);
        Wt_h[(16+g2*4+r)*WST + ct*16+lr] = f2h(acc1[r]);
      }
    }
  }
  __syncthreads();
  // ph3: outer products P[i][j] = x1[i]*sh[j]
  {
    float xv = x1_t[e*17+g];
    float shv[16];
    #pragma unroll
    for(int j=0;j<16;j++) shv[j]=sh_t[e*17+j];
    uint32_t* dst = (uint32_t*)AFh + e*132 + g*8;
    #pragma unroll
    for(int jp=0;jp<8;jp++)
      dst[jp] = (uint32_t)f2h(xv*shv[2*jp]) | ((uint32_t)f2h(xv*shv[2*jp+1])<<16);
  }
  __syncthreads();
  // ph4: branch-free cg contraction [40][16]
  {
    const uint2* cgt = (const uint2*)T->cg1p;
    #pragma unroll
    for(int p=0;p<3;p++){
      int slot = p*16+g;
      if(slot<40){
        float acc=0.f;
        #pragma unroll
        for(int q=0;q<16;q++){
          uint2 v = cgt[slot*16+q];
          acc += __uint_as_float(v.y) * h2f(AFh[e*264 + (v.x&0xff)]);
        }
        S16h[e*40+slot] = f2h(acc);
      }
    }
  }
  __syncthreads();
  // ph5: out phase
  float a0=0.f, a1=0.f, accB[3]={0.f,0.f,0.f}, accC[3]={0.f,0.f,0.f};
  {
    int grp = (g>=8)+(g>=12);
    int base = (grp==0)?0:((grp==1)?16:24);
    int ol = g*2 - base;
    #pragma unroll
    for(int p=0;p<4;p++){
      uint32_t v = T->tabA[grp*4+p];
      int w0 = v&0xffff, sb = v>>16;
      float Sv = h2f(S16h[e*40+sb]);
      uint32_t wp = *(const uint32_t*)(Wt_h + e*WST + w0 + ol);
      a0 += h2f((unsigned short)(wp&0xffff))*Sv;
      a1 += h2f((unsigned short)(wp>>16))*Sv;
    }
    #pragma unroll
    for(int p=0;p<6;p++){
      uint32_t v = T->tabB[p];
      int w0 = v&0xffff, sb = v>>16;
      float Wv = h2f(Wt_h[e*WST + w0 + g]);
      accB[0] += Wv*h2f(S16h[e*40+sb]);
      accB[1] += Wv*h2f(S16h[e*40+sb+1]);
      accB[2] += Wv*h2f(S16h[e*40+sb+2]);
    }
    #pragma unroll
    for(int p=0;p<3;p++){
      uint32_t v = T->tabC[p];
      int w0 = v&0xffff, sb = v>>16;
      float Wv = h2f(Wt_h[e*WST + w0 + g]);
      accC[0] += Wv*h2f(S16h[e*40+sb]);
      accC[1] += Wv*h2f(S16h[e*40+sb+1]);
      accC[2] += Wv*h2f(S16h[e*40+sb+2]);
    }
  }
  // two flush passes (no zero-fill: every (e,col) written exactly once;
  // tail edges produce zeros and are skipped via dst<0)
  #pragma unroll
  for(int h=0; h<2; h++){
    if(h==0){
      ef_h[e*65 + g*2]   = a0;
      ef_h[e*65 + g*2+1] = a1;
      #pragma unroll
      for(int k=0;k<3;k++){
        int b = g*3+k;
        if(b<32) ef_h[e*65 + 32+b] = accB[k];
      }
    } else {
      #pragma unroll
      for(int k=0;k<3;k++){
        int b = g*3+k;
        if(b>=32) ef_h[e*65 + (b-32)] = accB[k];
      }
      #pragma unroll
      for(int k=0;k<3;k++)
        ef_h[e*65 + 16 + g*3+k] = accC[k];
    }
    __syncthreads();
    if(t<64){
      int rank = h*64+t;
      int opos = rank<16? rank : rank<24? rank+16 : rank<32? rank+24 : rank+32;
      float acc=0.f;
      for(int e2=0;e2<TILE;e2++){
        int d = dst_t[e2];
        if(d>=0) acc += ef_h[e2*65+t];
        bool bnd = (e2==TILE-1) || (dst_t[e2+1]!=d);
        if(bnd){
          if(d>=0 && acc!=0.f) atomicAdd(&ef1[(size_t)d*160 + opos], acc);
          acc=0.f;
        }
      }
    }
    __syncthreads();
  }
}

__global__ void k_gate(const float* __restrict__ ef1, float* __restrict__ xg, int N, float inv_nn){
  int n = blockIdx.x*256+threadIdx.x;
  if(n>=N) return;
  const float* v = ef1 + (size_t)n*160;
  float* o = xg + (size_t)n*128;
  float g[32];
  #pragma unroll
  for(int i=0;i<16;i++) o[i] = fmaxf(v[i]*inv_nn, 0.f);
  #pragma unroll
  for(int i=0;i<16;i++) o[16+i] = tanhf(v[16+i]*inv_nn);
  #pragma unroll
  for(int i=0;i<8;i++) g[i]    = fmaxf(v[32+i]*inv_nn,0.f);
  #pragma unroll
  for(int i=0;i<8;i++) g[8+i]  = tanhf(v[40+i]*inv_nn);
  #pragma unroll
  for(int i=0;i<8;i++) g[16+i] = fmaxf(v[48+i]*inv_nn,0.f);
  #pragma unroll
  for(int i=0;i<8;i++) g[24+i] = tanhf(v[56+i]*inv_nn);
  #pragma unroll
  for(int u=0;u<32;u++){
    float gu = g[u];
    #pragma unroll
    for(int k=0;k<3;k++) o[32+u*3+k] = v[64+u*3+k]*inv_nn*gu;
  }
}

// LDS (floats) k_fc2_tp2 (512 threads):
//   sh @0 544 | emb @544 -> 1088 | xg @1088 [32][65] 2080 -> 3168
//   Wt @3168 f32[32][37] 1184 -> 4352
//   AF @4352 4096f (S_l f32 [32][33]=1056 aliases) -> 8448 | bins @8448 16
#define F2_WT 3168
#define F2_AF 4352
#define F2_BINS 8448
#define F2_TOT 8464

__global__ __launch_bounds__(512,6) void k_fc2_tp2(
    const float* __restrict__ pos, const int* __restrict__ esrc, const int* __restrict__ edst,
    const int* __restrict__ perm, const int* __restrict__ batch,
    const unsigned short* __restrict__ W1p, const unsigned short* __restrict__ B2,
    const float* __restrict__ xg, float* __restrict__ out,
    const TPTables* __restrict__ T, int E, float out_scale, int G)
{
  __shared__ __align__(16) float sm[F2_TOT];
  __shared__ int src_t[TILE], dst_t[TILE], g_t[TILE];
  float* sh_t  = sm;
  float* emb_t = sm + 544;
  float* xg_t  = sm + 1088;
  float* Wt    = sm + F2_WT;
  unsigned short* AFh = (unsigned short*)(sm + F2_AF);
  float* S_l  = sm + F2_AF;
  float* bins = sm + F2_BINS;
  int t = threadIdx.x;
  int e0 = blockIdx.x*TILE;
  int nE = min(TILE, E-e0);
  int e = t>>4, g = t&15, w = t>>6, lane = t&63;
  int g2 = lane>>4, lr = lane&15;

  if(t<TILE){
    float embr[10];
    if(t<nE){
      int e2 = perm[e0+t];
      int s=esrc[e2], d=edst[e2];
      src_t[t]=s; dst_t[t]=d; g_t[t]=batch[d];
      float ex=pos[3*d]-pos[3*s], ey=pos[3*d+1]-pos[3*s+1], ez=pos[3*d+2]-pos[3*s+2];
      float dd=sqrtf(ex*ex+ey*ey+ez*ez+1e-12f);
      sph16(ex/dd,ey/dd,ez/dd, &sh_t[t*17]);
      radial10(dd, embr);
    } else {
      src_t[t]=0; dst_t[t]=-1; g_t[t]=0;
      #pragma unroll
      for(int j=0;j<16;j++) sh_t[t*17+j]=0.f;
      #pragma unroll
      for(int b=0;b<10;b++) embr[b]=0.f;
    }
    #pragma unroll
    for(int b=0;b<10;b++) emb_t[t*17+b]=embr[b];
  } else if(t<TILE+16){
    bins[t-TILE]=0.f;
  }
  __syncthreads();
  #pragma unroll
  for(int rep=0;rep<4;rep++){
    int j = g + rep*16;
    xg_t[e*65+j] = xg[(size_t)src_t[e]*128 + (j<16? j : j+16)];
  }
  {
    float af0[8], af1[8];
    #pragma unroll
    for(int s=0;s<8;s++){
      int k = g2*4 + (s&3) + ((s>>2)<<4);
      af0[s] = (k<10)? emb_t[lr*17+k] : 0.f;
      af1[s] = (k<10)? emb_t[(16+lr)*17+k] : 0.f;
    }
    union { f16x8 v; uint32_t w4[4]; } a0u, a1u;
    #pragma unroll
    for(int i=0;i<4;i++){
      a0u.w4[i] = (uint32_t)f2h(af0[2*i]) | ((uint32_t)f2h(af0[2*i+1])<<16);
      a1u.w4[i] = (uint32_t)f2h(af1[2*i]) | ((uint32_t)f2h(af1[2*i+1])<<16);
    }
    #pragma unroll
    for(int q=0;q<2;q++){
      int ct = w*2+q;
      f16x8 b = *(const f16x8*)(W1p + ((size_t)(ct*64+lane))*8);
      f32x4 z = {0.f,0.f,0.f,0.f};
      f32x4 c0 = __builtin_amdgcn_mfma_f32_16x16x32_f16(a0u.v, b, z, 0,0,0);
      f32x4 c1 = __builtin_amdgcn_mfma_f32_16x16x32_f16(a1u.v, b, z, 0,0,0);
      int ks = ct>>1, sp = (lr&3)|((ct&1)<<2);
      #pragma unroll
      for(int r=0;r<4;r++){
        int lnp = ((lr>>2)<<4) + (g2<<2) + r;
        int sl = sig(lnp);
        AFh[(ks*64+sl)*8+sp]     = f2h(fmaxf(c0[r],0.f));
        AFh[((8+ks)*64+sl)*8+sp] = f2h(fmaxf(c1[r],0.f));
      }
    }
  }
  __syncthreads();
  {
    if(w<2){
      int ct = w;
      int sl = sig(lane);
      f32x4 acc0 = {0.f,0.f,0.f,0.f}, acc1 = {0.f,0.f,0.f,0.f};
      #pragma unroll
      for(int ks=0;ks<8;ks++){
        f16x8 b  = *(const f16x8*)(B2 + ((size_t)(ct*8+ks)*64 + lane)*8);
        f16x8 a0 = *(const f16x8*)(AFh + (ks*64+sl)*8);
        f16x8 a1 = *(const f16x8*)(AFh + ((8+ks)*64+sl)*8);
        acc0 = __builtin_amdgcn_mfma_f32_16x16x32_f16(a0, b, acc0, 0,0,0);
        acc1 = __builtin_amdgcn_mfma_f32_16x16x32_f16(a1, b, acc1, 0,0,0);
      }
      #pragma unroll
      for(int r=0;r<4;r++){
        Wt[(g2*4+r)*37 + ct*16+lr]    = acc0[r];
        Wt[(16+g2*4+r)*37 + ct*16+lr] = acc1[r];
      }
    }
  }
  __syncthreads();
  {
    const uint2* cgt = (const uint2*)T->cg2p;
    #pragma unroll
    for(int p=0;p<2;p++){
      int slot = p*16 + g;
      float acc=0.f;
      #pragma unroll
      for(int q=0;q<4;q++){
        uint2 v = cgt[slot*4+q];
        acc += __uint_as_float(v.y) * xg_t[e*65+(v.x&0xff)] * sh_t[e*17+((v.x>>8)&0xff)];
      }
      S_l[e*33+slot]=acc;
    }
  }
  __syncthreads();
  {
    uint32_t u0 = T->out2p[2*g], u1 = T->out2p[2*g+1];
    float v = Wt[e*37+(u0&0xffff)] * S_l[e*33+(u0>>16)]
            + Wt[e*37+(u1&0xffff)] * S_l[e*33+(u1>>16)];
    #pragma unroll
    for(int m=1;m<16;m<<=1) v += __shfl_xor(v, m, 64);
    if(g==0 && e<nE) atomicAdd(&bins[g_t[e]], v);
  }
  __syncthreads();
  if(t<G) atomicAdd(&out[t], bins[t]*out_scale);
}

// ---------------- launch ----------------
extern "C" void kernel_launch(void* const* d_in, const int* in_sizes, int n_in,
                              void* d_out, int out_size, void* d_ws, size_t ws_size,
                              hipStream_t stream) {
  const float* pos  = (const float*)d_in[0];
  const float* w11  = (const float*)d_in[1];
  const float* w12  = (const float*)d_in[2];
  const float* w21  = (const float*)d_in[3];
  const float* w22  = (const float*)d_in[4];
  const int*   esrc = (const int*)d_in[5];
  const int*   edst = (const int*)d_in[6];
  const int*   batch= (const int*)d_in[7];
  int E = in_sizes[5];
  int N = in_sizes[0]/3;
  int G = out_size;

  double nn = std::sqrt((double)E/(double)N);
  float inv_nn    = (float)(1.0/nn);
  float out_scale = (float)(1.0/(nn*std::sqrt((double)N)));

  float* ws = (float*)d_ws;
  float* x   = ws;
  float* ef1 = x   + (size_t)N*16;
  float* xg  = ef1 + (size_t)N*160;
  TPTables* dT = (TPTables*)(xg + (size_t)N*128);
  unsigned short* B1   = (unsigned short*)(((char*)dT) + ((sizeof(TPTables)+255)&~(size_t)255));
  unsigned short* B2   = B1 + NB1;
  unsigned short* W1p1 = B2 + NB2;
  unsigned short* W1p2 = W1p1 + NW1;
  int* deg    = (int*)(W1p2 + NW1);
  int* row    = deg + N;
  int* cursor = row + (N+1);
  int* perm   = cursor + N;

  static TPTables hT;
  build_tables(hT);
  hipMemcpyAsync(dT, &hT, sizeof(TPTables), hipMemcpyHostToDevice, stream);

  size_t nz = (size_t)N*16 + (size_t)N*160 + G + N;
  int zgrid = (int)((nz+255)/256); if(zgrid>2048) zgrid=2048;
  k_zero<<<zgrid,256,0,stream>>>(x, (size_t)N*16, ef1, (size_t)N*160, (float*)d_out, (size_t)G, deg, (size_t)N);
  k_deg<<<(E+255)/256,256,0,stream>>>(edst, deg, E);
  k_scan<<<1,1024,0,stream>>>(deg, row, cursor, N);
  k_fill<<<(E+255)/256,256,0,stream>>>(edst, row, cursor, perm, E);
  k_prep<<<(NB1+NB2+2*NW1+255)/256,256,0,stream>>>(w12, w22, w11, w21, B1, B2, W1p1, W1p2, dT);
  k_edge_pre<<<(E+255)/256,256,0,stream>>>(pos, esrc, edst, perm, x, E);
  k_fc1_tp1<<<(E+TILE-1)/TILE,512,0,stream>>>(pos, esrc, edst, perm, W1p1, B1, x, ef1, dT, E, inv_nn);
  k_gate<<<(N+255)/256,256,0,stream>>>(ef1, xg, N, inv_nn);
  k_fc2_tp2<<<(E+TILE-1)/TILE,512,0,stream>>>(pos, esrc, edst, perm, batch, W1p2, B2, xg,
                                              (float*)d_out, dT, E, out_scale, G);
}

// Round 10
// 905.829 us; speedup vs baseline: 1.2586x; 1.2010x over previous
//
#include <hip/hip_runtime.h>
#include <cmath>
#include <cstdint>
#include <cstring>
#include <cstdlib>
#include <vector>
#include <algorithm>
#include <complex>

#define TILE 32

typedef __attribute__((ext_vector_type(8))) _Float16 f16x8;
typedef __attribute__((ext_vector_type(4))) float f32x4;

// ------------------------------------------------------------------
// TP tables: trimmed cg [39][10] + overflow list; structural path
// tables for the out phase (fan 4/6/3 per class); alphas folded into W2.
// ------------------------------------------------------------------
struct TPTables {
  uint32_t cg1p[40*10*2];   // [slot][10] uint2 {prodidx(i*16+j), coefbits}
  uint32_t ovf[64*2];       // overflow: {prodidx | slot<<8, coefbits}
  int novf;
  uint32_t tabA[12];        // [grp(i3=0,2,4)][4 paths] = w0 | sbase<<16
  uint32_t tabB[6];         // i3=6 paths
  uint32_t tabC[3];         // i3=7 paths
  uint32_t cg2p[32*4*2];    // uint2 {i | j<<8, coefbits}
  uint32_t out2p[32];       // widx | s<<16
  float alpha1[272];
  float alpha2[32];
};

static double factd(int n){ double r=1; for(int i=2;i<=n;i++) r*=(double)i; return r; }

static double cg_complex(int j1,int m1,int j2,int m2,int j3,int m3){
  if(m1+m2!=m3) return 0.0;
  double pref = std::sqrt((2*j3+1)*factd(j3+j1-j2)*factd(j3-j1+j2)*factd(j1+j2-j3)/factd(j1+j2+j3+1));
  pref *= std::sqrt(factd(j3+m3)*factd(j3-m3)*factd(j1-m1)*factd(j1+m1)*factd(j2-m2)*factd(j2+m2));
  double s=0.0;
  for(int k=0;k<=j1+j2-j3;k++){
    int dd[6] = {k, j1+j2-j3-k, j1-m1-k, j2+m2-k, j3-j2+m1+k, j3-j1-m2+k};
    bool ok=true; double prod=1.0;
    for(int t=0;t<6;t++){ if(dd[t]<0){ok=false;break;} prod*=factd(dd[t]); }
    if(!ok) continue;
    s += ((k&1)?-1.0:1.0)/prod;
  }
  return pref*s;
}

typedef std::complex<double> cd;
static void real_U(int l, cd* U){
  int n = 2*l+1;
  for(int i=0;i<n*n;i++) U[i]=cd(0,0);
  U[l*n+l] = cd(1,0);
  for(int m=1;m<=l;m++){
    double sgn = (m&1)? -1.0 : 1.0;
    double is2 = 1.0/std::sqrt(2.0);
    U[(l+m)*n + (l+m)] = cd(sgn*is2,0);
    U[(l+m)*n + (l-m)] = cd(is2,0);
    U[(l-m)*n + (l+m)] = cd(0,-sgn*is2);
    U[(l-m)*n + (l-m)] = cd(0,is2);
  }
}

static void real_cg_h(int l1,int l2,int l3, double* out){
  int n1=2*l1+1,n2=2*l2+1,n3=2*l3+1;
  std::vector<cd> C(n1*n2*n3);
  for(int a=-l1;a<=l1;a++)for(int b=-l2;b<=l2;b++)for(int c=-l3;c<=l3;c++)
    C[(size_t)((a+l1)*n2+(b+l2))*n3+(c+l3)] = cd(cg_complex(l1,a,l2,b,l3,c),0);
  std::vector<cd> U1(n1*n1),U2(n2*n2),U3(n3*n3);
  real_U(l1,U1.data()); real_U(l2,U2.data()); real_U(l3,U3.data());
  std::vector<cd> T((size_t)n1*n2*n3, cd(0,0));
  for(int i=0;i<n1;i++)for(int j=0;j<n2;j++)for(int k=0;k<n3;k++){
    cd acc(0,0);
    for(int a=0;a<n1;a++){ cd u1=U1[i*n1+a]; if(u1==cd(0,0)) continue;
      for(int b=0;b<n2;b++){ cd u2=U2[j*n2+b]; if(u2==cd(0,0)) continue;
        for(int c=0;c<n3;c++){ cd u3=std::conj(U3[k*n3+c]); if(u3==cd(0,0)) continue;
          acc += u1*u2*u3*C[(size_t)(a*n2+b)*n3+c];
        } } }
    T[(size_t)(i*n2+j)*n3+k]=acc;
  }
  double sr=0, si=0;
  for(auto&z:T){ sr += std::fabs(z.real()); si += std::fabs(z.imag()); }
  int tot=n1*n2*n3;
  std::vector<double> R(tot);
  for(int i=0;i<tot;i++) R[i] = (sr>=si)? T[i].real() : T[i].imag();
  double nrm=0; for(double v:R) nrm += v*v; nrm = std::sqrt(nrm);
  for(int i=0;i<tot;i++) out[i] = R[i]/nrm;
}

struct HIrr{int m,l,p;};
static int map_id(int i){return i;}
static int map_gate(int i){return (i<16)? i : i-16;}

static void build_one(const std::vector<HIrr>& ir1, const std::vector<HIrr>& ir2,
                      const std::vector<HIrr>& ir3, int (*map1)(int),
                      std::vector<uint32_t>& cg_pk, std::vector<float>& cg_c,
                      std::vector<uint32_t>& out_pk, std::vector<float>& out_c)
{
  int n1=(int)ir1.size(), n2=(int)ir2.size(), n3=(int)ir3.size();
  std::vector<int> s1(n1), s2(n2), s3(n3);
  { int o=0; for(int i=0;i<n1;i++){ s1[i]=o; o+=ir1[i].m*(2*ir1[i].l+1);} }
  { int o=0; for(int i=0;i<n2;i++){ s2[i]=o; o+=ir2[i].m*(2*ir2[i].l+1);} }
  { int o=0; for(int i=0;i<n3;i++){ s3[i]=o; o+=ir3[i].m*(2*ir3[i].l+1);} }
  struct Inst{int i1,i2,i3,w0;};
  std::vector<Inst> insts; int woff=0;
  for(int i1=0;i1<n1;i1++)for(int i2=0;i2<n2;i2++)for(int i3=0;i3<n3;i3++){
    const HIrr&A=ir1[i1];const HIrr&B=ir2[i2];const HIrr&C=ir3[i3];
    int dl = A.l-B.l; if(dl<0) dl=-dl;
    if(A.p*B.p==C.p && dl<=C.l && C.l<=A.l+B.l){
      insts.push_back({i1,i2,i3,woff}); woff += A.m*B.m*C.m;
    }
  }
  std::vector<int> fan(n3,0);
  for(auto&P:insts) fan[P.i3] += ir1[P.i1].m*ir2[P.i2].m;
  int sbase=0;
  for(auto&P:insts){
    const HIrr&A=ir1[P.i1];const HIrr&B=ir2[P.i2];const HIrr&C=ir3[P.i3];
    int d1=2*A.l+1,d2=2*B.l+1,d3=2*C.l+1;
    double cg[343];
    real_cg_h(A.l,B.l,C.l,cg);
    double alpha = std::sqrt((double)d3/(double)fan[P.i3]);
    for(int u=0;u<A.m;u++)for(int v=0;v<B.m;v++){
      for(int k=0;k<d3;k++)
        for(int i=0;i<d1;i++)for(int j=0;j<d2;j++){
          double c = cg[(i*d2+j)*d3+k];
          if(std::fabs(c)<1e-8) continue;
          int iabs = map1(s1[P.i1]+u*d1+i);
          int jabs = s2[P.i2]+v*d2+j;
          cg_pk.push_back((uint32_t)iabs | ((uint32_t)jabs<<8) | ((uint32_t)(sbase+k)<<16));
          cg_c.push_back((float)c);
        }
      for(int w=0;w<C.m;w++)for(int k=0;k<d3;k++){
        out_pk.push_back((uint32_t)(s3[P.i3]+w*d3+k) | ((uint32_t)(P.w0+(u*B.m+v)*C.m+w)<<8) | ((uint32_t)(sbase+k)<<20));
        out_c.push_back((float)alpha);
      }
      sbase += d3;
    }
  }
}

static uint32_t fbits(float f){ uint32_t u; memcpy(&u,&f,4); return u; }

static void build_tables(TPTables& T){
  std::vector<HIrr> IR_SH   ={{1,0,1},{1,1,-1},{1,2,1},{1,3,-1}};
  std::vector<HIrr> GATE_IN ={{16,0,1},{16,0,-1},{8,0,1},{8,0,-1},{8,0,1},{8,0,-1},{16,1,-1},{16,1,1}};
  std::vector<HIrr> GATE_OUT={{16,0,1},{16,0,-1},{16,1,-1},{16,1,1}};
  std::vector<HIrr> IR_OUT  ={{1,0,1}};
  std::vector<uint32_t> cg1,o1,cg2,o2; std::vector<float> cg1c,o1c,cg2c,o2c;
  build_one(IR_SH,IR_SH,GATE_IN,map_id,cg1,cg1c,o1,o1c);
  build_one(GATE_OUT,IR_SH,IR_OUT,map_gate,cg2,cg2c,o2,o2c);
  memset(&T,0,sizeof(T));
  {
    int cnt[40]; memset(cnt,0,sizeof(cnt));
    for(size_t idx=0; idx<cg1.size(); ++idx){
      int i = cg1[idx]&0xff, j=(cg1[idx]>>8)&0xff, s=(int)(cg1[idx]>>16);
      uint32_t pidx = (uint32_t)(i*16+j);
      if(s<40 && cnt[s]<10){
        T.cg1p[(s*10+cnt[s])*2]   = pidx;
        T.cg1p[(s*10+cnt[s])*2+1] = fbits(cg1c[idx]);
        cnt[s]++;
      } else if(T.novf<64){
        T.ovf[T.novf*2]   = pidx | ((uint32_t)s<<8);
        T.ovf[T.novf*2+1] = fbits(cg1c[idx]);
        T.novf++;
      }
    }
  }
  {
    int GIl[8]={0,0,0,0,0,0,1,1}, GIp[8]={1,-1,1,-1,1,-1,-1,1}, GIm[8]={16,16,8,8,8,8,16,16};
    int SHl[4]={0,1,2,3}, SHp[4]={1,-1,1,-1};
    int w0=0, sb=0, nA0=0,nA1=0,nA2=0,nB=0,nC=0;
    for(int i1=0;i1<4;i1++)for(int i2=0;i2<4;i2++)for(int i3=0;i3<8;i3++){
      int dl=SHl[i1]-SHl[i2]; if(dl<0) dl=-dl;
      if(SHp[i1]*SHp[i2]==GIp[i3] && dl<=GIl[i3] && GIl[i3]<=SHl[i1]+SHl[i2]){
        uint32_t ent = (uint32_t)w0 | ((uint32_t)sb<<16);
        if(i3==0 && nA0<4) T.tabA[nA0++] = ent;
        else if(i3==2 && nA1<4) T.tabA[4+nA1++] = ent;
        else if(i3==4 && nA2<4) T.tabA[8+nA2++] = ent;
        else if(i3==6 && nB<6) T.tabB[nB++] = ent;
        else if(i3==7 && nC<3) T.tabC[nC++] = ent;
        w0 += GIm[i3];
        sb += 2*GIl[i3]+1;
      }
    }
  }
  for(size_t idx=0; idx<o1.size(); ++idx){
    int widx = (o1[idx]>>8)&0xfff;
    if(widx<272) T.alpha1[widx] = o1c[idx];
  }
  {
    int cnt[32]; memset(cnt,0,sizeof(cnt));
    for(size_t idx=0; idx<cg2.size(); ++idx){
      int s = (int)(cg2[idx]>>16);
      if(s<32 && cnt[s]<4){
        T.cg2p[(s*4+cnt[s])*2]   = cg2[idx]&0xFFFF;
        T.cg2p[(s*4+cnt[s])*2+1] = fbits(cg2c[idx]);
        cnt[s]++;
      }
    }
  }
  for(size_t idx=0; idx<o2.size() && idx<32; ++idx){
    int widx = (o2[idx]>>8)&0xfff;
    int s    = (int)(o2[idx]>>20);
    T.out2p[idx] = (uint32_t)widx | ((uint32_t)s<<16);
    if(widx<32) T.alpha2[widx] = o2c[idx];
  }
}

// ---------------- device helpers ----------------
__device__ __forceinline__ unsigned short f2h(float f){
  _Float16 h = (_Float16)f;
  unsigned short u; __builtin_memcpy(&u, &h, 2); return u;
}
__device__ __forceinline__ float h2f(unsigned short u){
  _Float16 h; __builtin_memcpy(&h, &u, 2); return (float)h;
}
// bank-spread involution on 6-bit slot ids: low3 ^= high3.
// b128 reads (8 consecutive lanes, bits0-2 vary): sig mod 8 bijective -> conflict-free.
// b16 stores (bits2-5 vary, bits0-1 fixed): sig mod 8 covers all 8 -> ~4-way (was 16-way).
__device__ __forceinline__ int sig(int x){ return x ^ (x>>3); }

__device__ __forceinline__ void sph16(float x,float y,float z,float* sh){
  float x2=x*x, y2=y*y, z2=z*z;
  const float SQ3=1.7320508075688772f, SQ5=2.23606797749979f, SQ7=2.6457513110645907f;
  const float SQ15=3.872983346207417f, SQ42=6.48074069840786f, SQ70=8.366600265340756f, SQ105=10.246950765959598f;
  sh[0]=1.f;
  sh[1]=SQ3*y;  sh[2]=SQ3*z;  sh[3]=SQ3*x;
  sh[4]=SQ15*x*y; sh[5]=SQ15*y*z; sh[6]=0.5f*SQ5*(3.f*z2-1.f); sh[7]=SQ15*x*z; sh[8]=0.5f*SQ15*(x2-y2);
  sh[9]=0.25f*SQ70*y*(3.f*x2-y2); sh[10]=SQ105*x*y*z; sh[11]=0.25f*SQ42*y*(5.f*z2-1.f);
  sh[12]=0.5f*SQ7*z*(5.f*z2-3.f); sh[13]=0.25f*SQ42*x*(5.f*z2-1.f);
  sh[14]=0.5f*SQ105*z*(x2-y2);    sh[15]=0.25f*SQ70*x*(x2-3.f*y2);
}

__device__ __forceinline__ void radial10(float d, float* emb){
  const float step = 0.2909090909090909f;
  #pragma unroll
  for(int b=0;b<10;b++){
    float c = step*(float)(b+1);
    float u = (d-c)/step;
    float u2 = u*u;
    float f = 0.f;
    if(u2<1.f) f = 1.14136f*__expf(-u2/fmaxf(1.f-u2,1e-6f));
    emb[b] = f*3.1622776601683795f;
  }
}

// ---------------- kernels ----------------
__global__ void k_zero(float* a, size_t na, float* b, size_t nb, float* c, size_t nc,
                       int* d, size_t nd){
  size_t total = na+nb+nc+nd;
  for(size_t i = (size_t)blockIdx.x*blockDim.x+threadIdx.x; i<total; i += (size_t)gridDim.x*blockDim.x){
    if(i<na) a[i]=0.f;
    else if(i<na+nb) b[i-na]=0.f;
    else if(i<na+nb+nc) c[i-na-nb]=0.f;
    else d[i-na-nb-nc]=0;
  }
}

__global__ void k_deg(const int* __restrict__ edst, int* __restrict__ deg, int E){
  int e = blockIdx.x*256 + threadIdx.x;
  if(e<E) atomicAdd(&deg[edst[e]], 1);
}

// multi-block scan: per-1024-block exclusive scan + block sums
__global__ __launch_bounds__(1024) void k_scan1(const int* __restrict__ deg, int* __restrict__ row,
                                                int* __restrict__ bsum, int N){
  __shared__ int buf[2][1024];
  int t = threadIdx.x;
  int i = blockIdx.x*1024 + t;
  int v = (i<N)? deg[i] : 0;
  int cur=0;
  buf[0][t]=v; __syncthreads();
  for(int off=1; off<1024; off<<=1){
    int val = buf[cur][t];
    if(t>=off) val += buf[cur][t-off];
    buf[cur^1][t]=val; __syncthreads();
    cur^=1;
  }
  if(i<N) row[i] = buf[cur][t] - v;
  if(t==1023) bsum[blockIdx.x] = buf[cur][t];
}
// single-wave inclusive scan of block sums (nb <= 64)
__global__ void k_scan2(int* __restrict__ bsum, int nb){
  int t = threadIdx.x;
  int v = (t<nb)? bsum[t] : 0;
  #pragma unroll
  for(int off=1; off<64; off<<=1){
    int u = __shfl_up(v, off, 64);
    if(t>=off) v += u;
  }
  if(t<nb) bsum[t] = v;
}
// add block offsets, zero cursor, write row[N]
__global__ void k_scan3(int* __restrict__ row, const int* __restrict__ bsum,
                        int* __restrict__ cursor, int N, int nb){
  int i = blockIdx.x*256 + threadIdx.x;
  if(i<N){
    int b = i>>10;
    if(b>0) row[i] += bsum[b-1];
    cursor[i]=0;
  }
  if(i==0) row[N] = bsum[nb-1];
}

__global__ void k_fill(const int* __restrict__ edst, const int* __restrict__ row,
                       int* __restrict__ cursor, int* __restrict__ perm, int E){
  int e = blockIdx.x*256 + threadIdx.x;
  if(e<E){
    int d = edst[e];
    int p = atomicAdd(&cursor[d], 1);
    perm[row[d]+p] = e;
  }
}

#define NB1 (17*8*64*8)
#define NB2 (2*8*64*8)
#define NW1 (16*64*8)
__global__ void k_prep(const float* __restrict__ W2a, const float* __restrict__ W2b,
                       const float* __restrict__ W1a, const float* __restrict__ W1b,
                       unsigned short* __restrict__ B1, unsigned short* __restrict__ B2,
                       unsigned short* __restrict__ W1p1, unsigned short* __restrict__ W1p2,
                       const TPTables* __restrict__ T){
  int i = blockIdx.x*256 + threadIdx.x;
  if(i < NB1){
    int s = i&7, lane = (i>>3)&63, ks = (i>>9)&7, ct = i>>12;
    int g = lane>>4;
    int k = ks*32 + g*4 + (s&3) + ((s>>2)<<4);
    int c = ct*16 + (lane&15);
    B1[i] = f2h(W2a[k*272+c]*0.0625f*T->alpha1[c]);
  } else if(i < NB1+NB2){
    int j = i - NB1;
    int s = j&7, lane = (j>>3)&63, ks = (j>>9)&7, ct = j>>12;
    int g = lane>>4;
    int k = ks*32 + g*4 + (s&3) + ((s>>2)<<4);
    int c = ct*16 + (lane&15);
    B2[j] = f2h(W2b[k*32+c]*0.0625f*T->alpha2[c]);
  } else if(i < NB1+NB2+NW1){
    int j = i - NB1 - NB2;
    int s = j&7, lane = (j>>3)&63, ct = j>>9;
    int g = lane>>4;
    int k = g*4 + (s&3) + ((s>>2)<<4);
    int c = ct*16 + (lane&15);
    W1p1[j] = (k<10)? f2h(W1a[k*256+c]*0.4472135954999579f) : (unsigned short)0;
  } else if(i < NB1+NB2+2*NW1){
    int j = i - NB1 - NB2 - NW1;
    int s = j&7, lane = (j>>3)&63, ct = j>>9;
    int g = lane>>4;
    int k = g*4 + (s&3) + ((s>>2)<<4);
    int c = ct*16 + (lane&15);
    W1p2[j] = (k<10)? f2h(W1b[k*256+c]*0.4472135954999579f) : (unsigned short)0;
  }
}

__global__ __launch_bounds__(256) void k_edge_pre(
    const float* __restrict__ pos, const int* __restrict__ esrc, const int* __restrict__ edst,
    const int* __restrict__ perm, float* __restrict__ x, int E){
  __shared__ float shs[256*17];
  __shared__ int dsts[256];
  int t = threadIdx.x;
  int idx = blockIdx.x*256 + t;
  int d = -1;
  if(idx<E){
    int e = perm[idx];
    int s = esrc[e]; d = edst[e];
    float ex=pos[3*d]-pos[3*s], ey=pos[3*d+1]-pos[3*s+1], ez=pos[3*d+2]-pos[3*s+2];
    float dd = sqrtf(ex*ex+ey*ey+ez*ez+1e-12f);
    sph16(ex/dd, ey/dd, ez/dd, &shs[t*17]);
  }
  dsts[t] = d;
  __syncthreads();
  bool leader = (d>=0) && (t==0 || dsts[t-1]!=d);
  if(leader){
    int len=1;
    while(t+len<256 && dsts[t+len]==d) len++;
    #pragma unroll
    for(int j=0;j<16;j++){
      float a=0.f;
      for(int k=0;k<len;k++) a += shs[(t+k)*17+j];
      atomicAdd(&x[(size_t)d*16+j], a);
    }
  }
}

// LDS (floats) k_fc1_tp1 (512 threads):
//   sh_t @0 [32][17] | x1_t @544 | emb_t @1088 -> 1632
//   Wt_h @1632 us[32][272] (4352f) -> 5984
//   AFh @5984: H-frags us[2][8][64][8]=8192us; P us[32][264]=8448us (4224f) -> 10208
//   S16 @10208 us[32][40]=1280us (640f) -> 10848
//   ef @10848 [32][65]=2080f -> 12928
#define F1_WT 1632
#define F1_AF 5984
#define F1_S  10208
#define F1_EF 10848
#define F1_TOT 12928

__global__ __launch_bounds__(512,6) void k_fc1_tp1(
    const float* __restrict__ pos, const int* __restrict__ esrc, const int* __restrict__ edst,
    const int* __restrict__ perm,
    const unsigned short* __restrict__ W1p, const unsigned short* __restrict__ B1,
    const float* __restrict__ xnode, float* __restrict__ ef1,
    const TPTables* __restrict__ T, int E, float inv_nn)
{
  __shared__ __align__(16) float sm[F1_TOT];
  __shared__ int src_t[TILE], dst_t[TILE];
  float* sh_t  = sm;
  float* x1_t  = sm + 544;
  float* emb_t = sm + 1088;
  unsigned short* Wt_h = (unsigned short*)(sm + F1_WT);
  unsigned short* AFh  = (unsigned short*)(sm + F1_AF);
  unsigned short* S16h = (unsigned short*)(sm + F1_S);
  float* ef_h = sm + F1_EF;
  int t = threadIdx.x;
  int e0 = blockIdx.x*TILE;
  int nE = min(TILE, E-e0);
  int e = t>>4, g = t&15, w = t>>6, lane = t&63;
  int g2 = lane>>4, lr = lane&15;

  if(t<TILE){
    float embr[10];
    if(t<nE){
      int e2 = perm[e0+t];
      int s=esrc[e2], d=edst[e2];
      src_t[t]=s; dst_t[t]=d;
      float ex=pos[3*d]-pos[3*s], ey=pos[3*d+1]-pos[3*s+1], ez=pos[3*d+2]-pos[3*s+2];
      float dd=sqrtf(ex*ex+ey*ey+ez*ez+1e-12f);
      sph16(ex/dd,ey/dd,ez/dd, &sh_t[t*17]);
      radial10(dd, embr);
    } else {
      src_t[t]=0; dst_t[t]=-1;
      #pragma unroll
      for(int j=0;j<16;j++) sh_t[t*17+j]=0.f;
      #pragma unroll
      for(int b=0;b<10;b++) embr[b]=0.f;
    }
    #pragma unroll
    for(int b=0;b<10;b++) emb_t[t*17+b]=embr[b];
  }
  __syncthreads();
  x1_t[e*17+g] = xnode[(size_t)src_t[e]*16+g]*inv_nn;
  // ph1: H = relu(emb @ W1p) -> A-fragment-major LDS (sig-swizzled slots)
  {
    float af0[8], af1[8];
    #pragma unroll
    for(int s=0;s<8;s++){
      int k = g2*4 + (s&3) + ((s>>2)<<4);
      af0[s] = (k<10)? emb_t[lr*17+k] : 0.f;
      af1[s] = (k<10)? emb_t[(16+lr)*17+k] : 0.f;
    }
    union { f16x8 v; uint32_t w4[4]; } a0u, a1u;
    #pragma unroll
    for(int i=0;i<4;i++){
      a0u.w4[i] = (uint32_t)f2h(af0[2*i]) | ((uint32_t)f2h(af0[2*i+1])<<16);
      a1u.w4[i] = (uint32_t)f2h(af1[2*i]) | ((uint32_t)f2h(af1[2*i+1])<<16);
    }
    #pragma unroll
    for(int q=0;q<2;q++){
      int ct = w*2+q;
      f16x8 b = *(const f16x8*)(W1p + ((size_t)(ct*64+lane))*8);
      f32x4 z = {0.f,0.f,0.f,0.f};
      f32x4 c0 = __builtin_amdgcn_mfma_f32_16x16x32_f16(a0u.v, b, z, 0,0,0);
      f32x4 c1 = __builtin_amdgcn_mfma_f32_16x16x32_f16(a1u.v, b, z, 0,0,0);
      int ks = ct>>1, sp = (lr&3)|((ct&1)<<2);
      #pragma unroll
      for(int r=0;r<4;r++){
        int lnp = ((lr>>2)<<4) + (g2<<2) + r;
        int sl = sig(lnp);
        AFh[(ks*64+sl)*8+sp]     = f2h(fmaxf(c0[r],0.f));
        AFh[((8+ks)*64+sl)*8+sp] = f2h(fmaxf(c1[r],0.f));
      }
    }
  }
  __syncthreads();
  // ph2: W = H @ B1 (sig-swizzled b128 A-frag reads — same slot set, conflict-free)
  {
    int sl = sig(lane);
    for(int ct=w; ct<17; ct+=8){
      f32x4 acc0 = {0.f,0.f,0.f,0.f}, acc1 = {0.f,0.f,0.f,0.f};
      #pragma unroll
      for(int ks=0;ks<8;ks++){
        f16x8 b  = *(const f16x8*)(B1 + ((size_t)(ct*8+ks)*64 + lane)*8);
        f16x8 a0 = *(const f16x8*)(AFh + (ks*64+sl)*8);
        f16x8 a1 = *(const f16x8*)(AFh + ((8+ks)*64+sl)*8);
        acc0 = __builtin_amdgcn_mfma_f32_16x16x32_f16(a0, b, acc0, 0,0,0);
        acc1 = __builtin_amdgcn_mfma_f32_16x16x32_f16(a1, b, acc1, 0,0,0);
      }
      #pragma unroll
      for(int r=0;r<4;r++){
        Wt_h[(g2*4+r)*272 + ct*16+lr]    = f2h(acc0[r]);
        Wt_h[(16+g2*4+r)*272 + ct*16+lr] = f2h(acc1[r]);
      }
    }
  }
  __syncthreads();
  // ph3: outer products P[i][j] = x1[i]*sh[j]
  {
    float xv = x1_t[e*17+g];
    float shv[16];
    #pragma unroll
    for(int j=0;j<16;j++) shv[j]=sh_t[e*17+j];
    uint32_t* dst = (uint32_t*)AFh + e*132 + g*8;
    #pragma unroll
    for(int jp=0;jp<8;jp++)
      dst[jp] = (uint32_t)f2h(xv*shv[2*jp]) | ((uint32_t)f2h(xv*shv[2*jp+1])<<16);
  }
  __syncthreads();
  // ph4: cg contraction [39][10] + overflow
  {
    const uint2* cgt = (const uint2*)T->cg1p;
    #pragma unroll
    for(int p=0;p<3;p++){
      int slot = p*16+g;
      if(slot<39){
        float acc=0.f;
        #pragma unroll
        for(int q=0;q<10;q++){
          uint2 v = cgt[slot*10+q];
          acc += __uint_as_float(v.y) * h2f(AFh[e*264 + (v.x&0xff)]);
        }
        S16h[e*40+slot] = f2h(acc);
      }
    }
  }
  __syncthreads();
  if(t<TILE){
    int n = T->novf;
    for(int o=0;o<n;o++){
      uint2 v = ((const uint2*)T->ovf)[o];
      int slot = (v.x>>8)&0xff;
      S16h[t*40+slot] = f2h(h2f(S16h[t*40+slot]) + __uint_as_float(v.y)*h2f(AFh[t*264+(v.x&0xff)]));
    }
  }
  __syncthreads();
  // ph5: out phase
  float a0=0.f, a1=0.f, accB[3]={0.f,0.f,0.f}, accC[3]={0.f,0.f,0.f};
  {
    int grp = (g>=8)+(g>=12);
    int base = (grp==0)?0:((grp==1)?16:24);
    int ol = g*2 - base;
    #pragma unroll
    for(int p=0;p<4;p++){
      uint32_t v = T->tabA[grp*4+p];
      int w0 = v&0xffff, sb = v>>16;
      float Sv = h2f(S16h[e*40+sb]);
      uint32_t wp = *(const uint32_t*)(Wt_h + e*272 + w0 + ol);
      a0 += h2f((unsigned short)(wp&0xffff))*Sv;
      a1 += h2f((unsigned short)(wp>>16))*Sv;
    }
    #pragma unroll
    for(int p=0;p<6;p++){
      uint32_t v = T->tabB[p];
      int w0 = v&0xffff, sb = v>>16;
      float Wv = h2f(Wt_h[e*272 + w0 + g]);
      accB[0] += Wv*h2f(S16h[e*40+sb]);
      accB[1] += Wv*h2f(S16h[e*40+sb+1]);
      accB[2] += Wv*h2f(S16h[e*40+sb+2]);
    }
    #pragma unroll
    for(int p=0;p<3;p++){
      uint32_t v = T->tabC[p];
      int w0 = v&0xffff, sb = v>>16;
      float Wv = h2f(Wt_h[e*272 + w0 + g]);
      accC[0] += Wv*h2f(S16h[e*40+sb]);
      accC[1] += Wv*h2f(S16h[e*40+sb+1]);
      accC[2] += Wv*h2f(S16h[e*40+sb+2]);
    }
  }
  #pragma unroll
  for(int h=0; h<2; h++){
    for(int i=t;i<TILE*65;i+=512) ef_h[i]=0.f;
    __syncthreads();
    if(h==0){
      ef_h[e*65 + g*2]   = a0;
      ef_h[e*65 + g*2+1] = a1;
      #pragma unroll
      for(int k=0;k<3;k++){
        int b = g*3+k;
        if(b<32) ef_h[e*65 + 32+b] = accB[k];
      }
    } else {
      #pragma unroll
      for(int k=0;k<3;k++){
        int b = g*3+k;
        if(b>=32) ef_h[e*65 + (b-32)] = accB[k];
      }
      #pragma unroll
      for(int k=0;k<3;k++)
        ef_h[e*65 + 16 + g*3+k] = accC[k];
    }
    __syncthreads();
    if(t<64){
      int rank = h*64+t;
      int opos = rank<16? rank : rank<24? rank+16 : rank<32? rank+24 : rank+32;
      float acc=0.f;
      for(int e2=0;e2<TILE;e2++){
        int d = dst_t[e2];
        if(d>=0) acc += ef_h[e2*65+t];
        bool bnd = (e2==TILE-1) || (dst_t[e2+1]!=d);
        if(bnd){
          if(d>=0 && acc!=0.f) atomicAdd(&ef1[(size_t)d*160 + opos], acc);
          acc=0.f;
        }
      }
    }
    __syncthreads();
  }
}

__global__ void k_gate(const float* __restrict__ ef1, float* __restrict__ xg, int N, float inv_nn){
  int n = blockIdx.x*256+threadIdx.x;
  if(n>=N) return;
  const float* v = ef1 + (size_t)n*160;
  float* o = xg + (size_t)n*128;
  float g[32];
  #pragma unroll
  for(int i=0;i<16;i++) o[i] = fmaxf(v[i]*inv_nn, 0.f);
  #pragma unroll
  for(int i=0;i<16;i++) o[16+i] = tanhf(v[16+i]*inv_nn);
  #pragma unroll
  for(int i=0;i<8;i++) g[i]    = fmaxf(v[32+i]*inv_nn,0.f);
  #pragma unroll
  for(int i=0;i<8;i++) g[8+i]  = tanhf(v[40+i]*inv_nn);
  #pragma unroll
  for(int i=0;i<8;i++) g[16+i] = fmaxf(v[48+i]*inv_nn,0.f);
  #pragma unroll
  for(int i=0;i<8;i++) g[24+i] = tanhf(v[56+i]*inv_nn);
  #pragma unroll
  for(int u=0;u<32;u++){
    float gu = g[u];
    #pragma unroll
    for(int k=0;k<3;k++) o[32+u*3+k] = v[64+u*3+k]*inv_nn*gu;
  }
}

// LDS (floats) k_fc2_tp2 (512 threads):
//   sh @0 544 | emb @544 -> 1088 | xg @1088 [32][65] 2080 -> 3168
//   Wt @3168 f32[32][36] 1152 -> 4320
//   AF @4320 4096f (S_l f32 [32][33]=1056 aliases) -> 8416 | bins @8416 16
#define F2_WT 3168
#define F2_AF 4320
#define F2_BINS 8416
#define F2_TOT 8432

__global__ __launch_bounds__(512,6) void k_fc2_tp2(
    const float* __restrict__ pos, const int* __restrict__ esrc, const int* __restrict__ edst,
    const int* __restrict__ perm, const int* __restrict__ batch,
    const unsigned short* __restrict__ W1p, const unsigned short* __restrict__ B2,
    const float* __restrict__ xg, float* __restrict__ out,
    const TPTables* __restrict__ T, int E, float out_scale, int G)
{
  __shared__ __align__(16) float sm[F2_TOT];
  __shared__ int src_t[TILE], dst_t[TILE], g_t[TILE];
  float* sh_t  = sm;
  float* emb_t = sm + 544;
  float* xg_t  = sm + 1088;
  float* Wt    = sm + F2_WT;
  unsigned short* AFh = (unsigned short*)(sm + F2_AF);
  float* S_l  = sm + F2_AF;
  float* bins = sm + F2_BINS;
  int t = threadIdx.x;
  int e0 = blockIdx.x*TILE;
  int nE = min(TILE, E-e0);
  int e = t>>4, g = t&15, w = t>>6, lane = t&63;
  int g2 = lane>>4, lr = lane&15;

  if(t<TILE){
    float embr[10];
    if(t<nE){
      int e2 = perm[e0+t];
      int s=esrc[e2], d=edst[e2];
      src_t[t]=s; dst_t[t]=d; g_t[t]=batch[d];
      float ex=pos[3*d]-pos[3*s], ey=pos[3*d+1]-pos[3*s+1], ez=pos[3*d+2]-pos[3*s+2];
      float dd=sqrtf(ex*ex+ey*ey+ez*ez+1e-12f);
      sph16(ex/dd,ey/dd,ez/dd, &sh_t[t*17]);
      radial10(dd, embr);
    } else {
      src_t[t]=0; dst_t[t]=-1; g_t[t]=0;
      #pragma unroll
      for(int j=0;j<16;j++) sh_t[t*17+j]=0.f;
      #pragma unroll
      for(int b=0;b<10;b++) embr[b]=0.f;
    }
    #pragma unroll
    for(int b=0;b<10;b++) emb_t[t*17+b]=embr[b];
  } else if(t<TILE+16){
    bins[t-TILE]=0.f;
  }
  __syncthreads();
  #pragma unroll
  for(int rep=0;rep<4;rep++){
    int j = g + rep*16;
    xg_t[e*65+j] = xg[(size_t)src_t[e]*128 + (j<16? j : j+16)];
  }
  {
    float af0[8], af1[8];
    #pragma unroll
    for(int s=0;s<8;s++){
      int k = g2*4 + (s&3) + ((s>>2)<<4);
      af0[s] = (k<10)? emb_t[lr*17+k] : 0.f;
      af1[s] = (k<10)? emb_t[(16+lr)*17+k] : 0.f;
    }
    union { f16x8 v; uint32_t w4[4]; } a0u, a1u;
    #pragma unroll
    for(int i=0;i<4;i++){
      a0u.w4[i] = (uint32_t)f2h(af0[2*i]) | ((uint32_t)f2h(af0[2*i+1])<<16);
      a1u.w4[i] = (uint32_t)f2h(af1[2*i]) | ((uint32_t)f2h(af1[2*i+1])<<16);
    }
    #pragma unroll
    for(int q=0;q<2;q++){
      int ct = w*2+q;
      f16x8 b = *(const f16x8*)(W1p + ((size_t)(ct*64+lane))*8);
      f32x4 z = {0.f,0.f,0.f,0.f};
      f32x4 c0 = __builtin_amdgcn_mfma_f32_16x16x32_f16(a0u.v, b, z, 0,0,0);
      f32x4 c1 = __builtin_amdgcn_mfma_f32_16x16x32_f16(a1u.v, b, z, 0,0,0);
      int ks = ct>>1, sp = (lr&3)|((ct&1)<<2);
      #pragma unroll
      for(int r=0;r<4;r++){
        int lnp = ((lr>>2)<<4) + (g2<<2) + r;
        int sl = sig(lnp);
        AFh[(ks*64+sl)*8+sp]     = f2h(fmaxf(c0[r],0.f));
        AFh[((8+ks)*64+sl)*8+sp] = f2h(fmaxf(c1[r],0.f));
      }
    }
  }
  __syncthreads();
  {
    if(w<2){
      int ct = w;
      int sl = sig(lane);
      f32x4 acc0 = {0.f,0.f,0.f,0.f}, acc1 = {0.f,0.f,0.f,0.f};
      #pragma unroll
      for(int ks=0;ks<8;ks++){
        f16x8 b  = *(const f16x8*)(B2 + ((size_t)(ct*8+ks)*64 + lane)*8);
        f16x8 a0 = *(const f16x8*)(AFh + (ks*64+sl)*8);
        f16x8 a1 = *(const f16x8*)(AFh + ((8+ks)*64+sl)*8);
        acc0 = __builtin_amdgcn_mfma_f32_16x16x32_f16(a0, b, acc0, 0,0,0);
        acc1 = __builtin_amdgcn_mfma_f32_16x16x32_f16(a1, b, acc1, 0,0,0);
      }
      #pragma unroll
      for(int r=0;r<4;r++){
        Wt[(g2*4+r)*36 + ct*16+lr]    = acc0[r];
        Wt[(16+g2*4+r)*36 + ct*16+lr] = acc1[r];
      }
    }
  }
  __syncthreads();
  {
    const uint2* cgt = (const uint2*)T->cg2p;
    #pragma unroll
    for(int p=0;p<2;p++){
      int slot = p*16 + g;
      float acc=0.f;
      #pragma unroll
      for(int q=0;q<4;q++){
        uint2 v = cgt[slot*4+q];
        acc += __uint_as_float(v.y) * xg_t[e*65+(v.x&0xff)] * sh_t[e*17+((v.x>>8)&0xff)];
      }
      S_l[e*33+slot]=acc;
    }
  }
  __syncthreads();
  {
    uint32_t u0 = T->out2p[2*g], u1 = T->out2p[2*g+1];
    float v = Wt[e*36+(u0&0xffff)] * S_l[e*33+(u0>>16)]
            + Wt[e*36+(u1&0xffff)] * S_l[e*33+(u1>>16)];
    #pragma unroll
    for(int m=1;m<16;m<<=1) v += __shfl_xor(v, m, 64);
    if(g==0 && e<nE) atomicAdd(&bins[g_t[e]], v);
  }
  __syncthreads();
  if(t<G) atomicAdd(&out[t], bins[t]*out_scale);
}

// ---------------- launch ----------------
extern "C" void kernel_launch(void* const* d_in, const int* in_sizes, int n_in,
                              void* d_out, int out_size, void* d_ws, size_t ws_size,
                              hipStream_t stream) {
  const float* pos  = (const float*)d_in[0];
  const float* w11  = (const float*)d_in[1];
  const float* w12  = (const float*)d_in[2];
  const float* w21  = (const float*)d_in[3];
  const float* w22  = (const float*)d_in[4];
  const int*   esrc = (const int*)d_in[5];
  const int*   edst = (const int*)d_in[6];
  const int*   batch= (const int*)d_in[7];
  int E = in_sizes[5];
  int N = in_sizes[0]/3;
  int G = out_size;

  double nn = std::sqrt((double)E/(double)N);
  float inv_nn    = (float)(1.0/nn);
  float out_scale = (float)(1.0/(nn*std::sqrt((double)N)));

  float* ws = (float*)d_ws;
  float* x   = ws;
  float* ef1 = x   + (size_t)N*16;
  float* xg  = ef1 + (size_t)N*160;
  TPTables* dT = (TPTables*)(xg + (size_t)N*128);
  unsigned short* B1   = (unsigned short*)(((char*)dT) + ((sizeof(TPTables)+255)&~(size_t)255));
  unsigned short* B2   = B1 + NB1;
  unsigned short* W1p1 = B2 + NB2;
  unsigned short* W1p2 = W1p1 + NW1;
  int* deg    = (int*)(W1p2 + NW1);
  int* row    = deg + N;
  int* cursor = row + (N+1);
  int* perm   = cursor + N;
  int* bsum   = perm + E;

  static TPTables hT;
  build_tables(hT);
  hipMemcpyAsync(dT, &hT, sizeof(TPTables), hipMemcpyHostToDevice, stream);

  int nb = (N+1023)/1024;
  size_t nz = (size_t)N*16 + (size_t)N*160 + G + N;
  int zgrid = (int)((nz+255)/256); if(zgrid>2048) zgrid=2048;
  k_zero<<<zgrid,256,0,stream>>>(x, (size_t)N*16, ef1, (size_t)N*160, (float*)d_out, (size_t)G, deg, (size_t)N);
  k_deg<<<(E+255)/256,256,0,stream>>>(edst, deg, E);
  k_scan1<<<nb,1024,0,stream>>>(deg, row, bsum, N);
  k_scan2<<<1,64,0,stream>>>(bsum, nb);
  k_scan3<<<(N+255)/256,256,0,stream>>>(row, bsum, cursor, N, nb);
  k_fill<<<(E+255)/256,256,0,stream>>>(edst, row, cursor, perm, E);
  k_prep<<<(NB1+NB2+2*NW1+255)/256,256,0,stream>>>(w12, w22, w11, w21, B1, B2, W1p1, W1p2, dT);
  k_edge_pre<<<(E+255)/256,256,0,stream>>>(pos, esrc, edst, perm, x, E);
  k_fc1_tp1<<<(E+TILE-1)/TILE,512,0,stream>>>(pos, esrc, edst, perm, W1p1, B1, x, ef1, dT, E, inv_nn);
  k_gate<<<(N+255)/256,256,0,stream>>>(ef1, xg, N, inv_nn);
  k_fc2_tp2<<<(E+TILE-1)/TILE,512,0,stream>>>(pos, esrc, edst, perm, batch, W1p2, B2, xg,
                                              (float*)d_out, dT, E, out_scale, G);
}